// Round 9
// baseline (244.322 us; speedup 1.0000x reference)
//
#include <hip/hip_runtime.h>
#include <hip/hip_bf16.h>

#define NH   16
#define HD   64
#define HID  1024
#define TSEQ 2048
#define BATCH 2
#define KSCALE 0.18033688011112042f   // 0.125 * log2(e), folded into Wk/bk

typedef __attribute__((ext_vector_type(4))) float f32x4;
typedef __attribute__((ext_vector_type(8))) short s16x8;
typedef __attribute__((ext_vector_type(4))) short s16x4;
typedef __attribute__((ext_vector_type(8))) _Float16 f16x8;
typedef __attribute__((ext_vector_type(4))) _Float16 f16x4;
typedef __attribute__((ext_vector_type(2))) _Float16 f16x2;

__device__ __forceinline__ unsigned short f2bf(float f) {
  union { float f; unsigned int u; } v; v.f = f;
  unsigned int r = v.u + 0x7fffu + ((v.u >> 16) & 1u);
  return (unsigned short)(r >> 16);
}
__device__ __forceinline__ float bf2f(unsigned short b) {
  union { unsigned int u; float f; } v; v.u = ((unsigned int)b) << 16; return v.f;
}

__device__ __forceinline__ void async_cp16(const unsigned short* g, unsigned short* l) {
  __builtin_amdgcn_global_load_lds(
      (const __attribute__((address_space(1))) unsigned int*)g,
      (__attribute__((address_space(3))) unsigned int*)l, 16, 0, 0);
}

// ---------------- one cast kernel: h + all 4 weights (Wk pre-scaled) ----------------
__global__ __launch_bounds__(256) void cast_all_k(
    const float* __restrict__ h,
    const float* __restrict__ w0, const float* __restrict__ w1,
    const float* __restrict__ w2, const float* __restrict__ w3,
    unsigned short* __restrict__ hb, unsigned short* __restrict__ wbase) {
  int i = blockIdx.x * 256 + threadIdx.x;  // 2097152 float4 total
  const float* src; unsigned short* dst; int idx; float sc = 1.f;
  if (i < 1048576) { src = h; dst = hb; idx = i; }
  else {
    int idx4 = i - 1048576;
    int w = idx4 >> 18;
    idx = idx4 & 262143;
    src = (w == 0) ? w0 : (w == 1) ? w1 : (w == 2) ? w2 : w3;
    dst = wbase + (size_t)(idx4 - idx) * 4;   // contiguous weight region
    if (w == 1) sc = KSCALE;
  }
  float4 v = ((const float4*)src)[idx];
  ushort4 o;
  o.x = f2bf(v.x * sc); o.y = f2bf(v.y * sc); o.z = f2bf(v.z * sc); o.w = f2bf(v.w * sc);
  ((ushort4*)dst)[idx] = o;
}

// ---------------- GEMM core: C[128x128] += A[128xK] * B[128xK]^T ----------------
__device__ __forceinline__ void gemm_core(const unsigned short* __restrict__ Ag,
                                          const unsigned short* __restrict__ Bg,
                                          unsigned short* Ash, unsigned short* Bsh,
                                          f32x4 acc[4][4]) {
  const int tid  = threadIdx.x;
  const int lane = tid & 63;
  const int wave = tid >> 6;
  const int l15  = lane & 15;
  const int quad = lane >> 4;
  const int wm   = (wave >> 1) * 64;
  const int wn   = (wave & 1) * 64;
  const int idx0 = tid * 8;
  const int idx1 = idx0 + 2048;
  const int r0 = idx0 >> 5, c0 = idx0 & 31;
  const int r1 = idx1 >> 5, c1 = idx1 & 31;
#pragma unroll
  for (int i = 0; i < 4; ++i)
#pragma unroll
    for (int j = 0; j < 4; ++j) acc[i][j] = f32x4{0.f, 0.f, 0.f, 0.f};

  for (int k0 = 0; k0 < HID; k0 += 32) {
    __syncthreads();
    async_cp16(Ag + r0 * HID + k0 + c0, Ash + idx0);
    async_cp16(Ag + r1 * HID + k0 + c1, Ash + idx1);
    async_cp16(Bg + r0 * HID + k0 + c0, Bsh + idx0);
    async_cp16(Bg + r1 * HID + k0 + c1, Bsh + idx1);
    __syncthreads();
    s16x8 af[4], bfr[4];
#pragma unroll
    for (int i = 0; i < 4; ++i)
      af[i] = *(const s16x8*)(Ash + (wm + i * 16 + l15) * 32 + quad * 8);
#pragma unroll
    for (int j = 0; j < 4; ++j)
      bfr[j] = *(const s16x8*)(Bsh + (wn + j * 16 + l15) * 32 + quad * 8);
#pragma unroll
    for (int i = 0; i < 4; ++i)
#pragma unroll
      for (int j = 0; j < 4; ++j)
        acc[i][j] = __builtin_amdgcn_mfma_f32_16x16x32_bf16(af[i], bfr[j], acc[i][j], 0, 0, 0);
  }
}

// ---------------- QKV projection; V written f16-transposed [B,NH,D,T] ----------------
__global__ __launch_bounds__(256) void gemm_qkv(
    const unsigned short* __restrict__ hb,
    const unsigned short* __restrict__ wq, const unsigned short* __restrict__ wk,
    const unsigned short* __restrict__ wv,
    const float* __restrict__ bq, const float* __restrict__ bk, const float* __restrict__ bv,
    unsigned short* __restrict__ qo, unsigned short* __restrict__ ko,
    unsigned short* __restrict__ vto) {
  __shared__ unsigned short Ash[128 * 32];
  __shared__ unsigned short Bsh[128 * 32];
  const unsigned short* Bw; const float* bias; float bsc = 1.f;
  if (blockIdx.z == 0)      { Bw = wq; bias = bq; }
  else if (blockIdx.z == 1) { Bw = wk; bias = bk; bsc = KSCALE; }
  else                      { Bw = wv; bias = bv; }
  const int bm = blockIdx.y * 128, bn = blockIdx.x * 128;
  f32x4 acc[4][4];
  gemm_core(hb + (size_t)bm * HID, Bw + (size_t)bn * HID, Ash, Bsh, acc);

  const int tid = threadIdx.x, lane = tid & 63, wave = tid >> 6;
  const int l15 = lane & 15, quad = lane >> 4;
  const int wm = (wave >> 1) * 64, wn = (wave & 1) * 64;
  if (blockIdx.z == 2) {
    // V: f16, transposed to [B,NH,D,T]; 4 consecutive t per lane = 8B store
#pragma unroll
    for (int j = 0; j < 4; ++j) {
      const int col = bn + wn + j * 16 + l15;
      const float bb = bias[col];
      const int head = col >> 6, d = col & 63;
#pragma unroll
      for (int i = 0; i < 4; ++i) {
        const int row0 = bm + wm + i * 16 + quad * 4;
        const int bI = row0 >> 11, t0 = row0 & 2047;
        unsigned short o[4];
#pragma unroll
        for (int r = 0; r < 4; ++r) {
          _Float16 hv = (_Float16)(acc[i][j][r] + bb);
          o[r] = __builtin_bit_cast(unsigned short, hv);
        }
        *(s16x4*)(vto + ((size_t)((bI * NH + head) * HD + d)) * TSEQ + t0) = *(const s16x4*)o;
      }
    }
  } else {
    unsigned short* outp = (blockIdx.z == 0) ? qo : ko;
#pragma unroll
    for (int j = 0; j < 4; ++j) {
      const int col = bn + wn + j * 16 + l15;
      const float bb = bias[col] * bsc;
      const int head = col >> 6, d = col & 63;
#pragma unroll
      for (int i = 0; i < 4; ++i) {
#pragma unroll
        for (int r = 0; r < 4; ++r) {
          const int row = bm + wm + i * 16 + quad * 4 + r;  // row = b*T + t
          const int bI = row >> 11, t = row & 2047;
          outp[(((size_t)(bI * NH + head) * TSEQ) + t) * HD + d] = f2bf(acc[i][j][r] + bb);
        }
      }
    }
  }
}

// ---------------- Output projection, 128x64 tiles: out = ctx @ Wo^T + bo + h ----------------
__global__ __launch_bounds__(256) void gemm_out(
    const unsigned short* __restrict__ ctx, const unsigned short* __restrict__ wo,
    const float* __restrict__ bo, const float* __restrict__ hres,
    float* __restrict__ outf) {
  __shared__ unsigned short Ash[128 * 32];
  __shared__ unsigned short Bsh[64 * 32];
  const int tid = threadIdx.x, lane = tid & 63, wave = tid >> 6;
  const int l15 = lane & 15, quad = lane >> 4;
  const int wm = (wave >> 1) * 64, wn = (wave & 1) * 32;
  const int bm = blockIdx.y * 128, bn = blockIdx.x * 64;
  const unsigned short* Ag = ctx + (size_t)bm * HID;
  const unsigned short* Bg = wo + (size_t)bn * HID;
  const int idx0 = tid * 8, idx1 = idx0 + 2048;
  const int r0 = idx0 >> 5, c0 = idx0 & 31;
  const int r1 = idx1 >> 5, c1 = idx1 & 31;
  f32x4 acc[4][2];
#pragma unroll
  for (int i = 0; i < 4; ++i)
#pragma unroll
    for (int j = 0; j < 2; ++j) acc[i][j] = f32x4{0.f, 0.f, 0.f, 0.f};

  for (int k0 = 0; k0 < HID; k0 += 32) {
    __syncthreads();
    async_cp16(Ag + r0 * HID + k0 + c0, Ash + idx0);
    async_cp16(Ag + r1 * HID + k0 + c1, Ash + idx1);
    async_cp16(Bg + r0 * HID + k0 + c0, Bsh + idx0);
    __syncthreads();
    s16x8 af[4], bfr[2];
#pragma unroll
    for (int i = 0; i < 4; ++i)
      af[i] = *(const s16x8*)(Ash + (wm + i * 16 + l15) * 32 + quad * 8);
#pragma unroll
    for (int j = 0; j < 2; ++j)
      bfr[j] = *(const s16x8*)(Bsh + (wn + j * 16 + l15) * 32 + quad * 8);
#pragma unroll
    for (int i = 0; i < 4; ++i)
#pragma unroll
      for (int j = 0; j < 2; ++j)
        acc[i][j] = __builtin_amdgcn_mfma_f32_16x16x32_bf16(af[i], bfr[j], acc[i][j], 0, 0, 0);
  }
#pragma unroll
  for (int j = 0; j < 2; ++j) {
    const int col = bn + wn + j * 16 + l15;
    const float bb = bo[col];
#pragma unroll
    for (int i = 0; i < 4; ++i) {
#pragma unroll
      for (int r = 0; r < 4; ++r) {
        const int row = bm + wm + i * 16 + quad * 4 + r;
        const size_t off = (size_t)row * HID + col;
        outf[off] = acc[i][j][r] + bb + hres[off];
      }
    }
  }
}

// ---------------- Flash attention: S^T formulation, K-split by 1/2/4 ----------------
// Q bf16, K bf16 (pre-scaled), V f16 [B,NH,D,T].
// blockIdx.z = b << lsplit | part; each block handles ntiles = 32>>lsplit K-tiles.
__global__ __launch_bounds__(256, 2) void attn_k(
    const unsigned short* __restrict__ qb, const unsigned short* __restrict__ kb,
    const unsigned short* __restrict__ vt, unsigned short* __restrict__ ctx,
    unsigned short* __restrict__ Opart, float* __restrict__ rsumP,
    int lsplit, int ntiles) {
  __shared__ unsigned short Ksh[64 * 72];   // bf16 [key][d]
  __shared__ unsigned short Vsh[64 * 72];   // f16  [d][key]

  const int tid = threadIdx.x, lane = tid & 63, wave = tid >> 6;
  const int l15 = lane & 15, quad = lane >> 4;
  const int z = blockIdx.z;
  const int b = z >> lsplit;
  const int part = z & ((1 << lsplit) - 1);
  const int h = blockIdx.y, qt = blockIdx.x;
  const size_t ho = ((size_t)(b * NH + h)) * TSEQ * HD;
  const unsigned short* Qh = qb + ho;
  const unsigned short* Kh = kb + ho;
  const unsigned short* Vh = vt + ho;
  const int q0 = qt * 128 + wave * 32;
  const int kt0 = part * ntiles;

  // Q fragments (B-operand of S^T): col q=l15, k over d
  s16x8 qf[2][2];
#pragma unroll
  for (int s = 0; s < 2; ++s)
#pragma unroll
    for (int ks = 0; ks < 2; ++ks)
      qf[s][ks] = *(const s16x8*)(Qh + (size_t)(q0 + s * 16 + l15) * HD + ks * 32 + quad * 8);

  f32x4 accO[4][2];   // O^T: [d-strip n2][q-col s], lane=(d=quad*4+r, q=l15)
  float rsum[2];      // per-lane: q = s*16 + l15
#pragma unroll
  for (int n2 = 0; n2 < 4; ++n2)
#pragma unroll
    for (int s = 0; s < 2; ++s) accO[n2][s] = f32x4{0.f, 0.f, 0.f, 0.f};
  rsum[0] = rsum[1] = 0.f;

  const int sr = tid >> 3, sc = (tid & 7) * 8;
  s16x8 kreg[2], vreg[2];
#pragma unroll
  for (int hf = 0; hf < 2; ++hf) {
    kreg[hf] = *(const s16x8*)(Kh + (size_t)(kt0 * 64 + sr + hf * 32) * HD + sc);
    vreg[hf] = *(const s16x8*)(Vh + (size_t)(sr + hf * 32) * TSEQ + kt0 * 64 + sc);
  }

  for (int kt = 0; kt < ntiles; ++kt) {
    __syncthreads();
#pragma unroll
    for (int hf = 0; hf < 2; ++hf) {
      *(s16x8*)(Ksh + (sr + hf * 32) * 72 + sc) = kreg[hf];
      *(s16x8*)(Vsh + (sr + hf * 32) * 72 + sc) = vreg[hf];
    }
    __syncthreads();
    if (kt + 1 < ntiles) {
      const int k0n = (kt0 + kt + 1) * 64;
#pragma unroll
      for (int hf = 0; hf < 2; ++hf) {
        kreg[hf] = *(const s16x8*)(Kh + (size_t)(k0n + sr + hf * 32) * HD + sc);
        vreg[hf] = *(const s16x8*)(Vh + (size_t)(sr + hf * 32) * TSEQ + k0n + sc);
      }
    }

    // S^T = K·Q^T: A = K-frag (row=key), B = Q-frag (col=q)
    f32x4 accS[2][4];   // [q-col s][key-strip n]
#pragma unroll
    for (int s = 0; s < 2; ++s)
#pragma unroll
      for (int n = 0; n < 4; ++n) accS[s][n] = f32x4{0.f, 0.f, 0.f, 0.f};
#pragma unroll
    for (int ks = 0; ks < 2; ++ks) {
#pragma unroll
      for (int n = 0; n < 4; ++n) {
        s16x8 kf = *(const s16x8*)(Ksh + (n * 16 + l15) * 72 + ks * 32 + quad * 8);
#pragma unroll
        for (int s = 0; s < 2; ++s)
          accS[s][n] = __builtin_amdgcn_mfma_f32_16x16x32_bf16(kf, qf[s][ks], accS[s][n], 0, 0, 0);
      }
    }

    // exp in-register; packed cvt; result IS the PV B-fragment
    f16x4 pB[2][4];
#pragma unroll
    for (int s = 0; s < 2; ++s)
#pragma unroll
      for (int n = 0; n < 4; ++n) {
        float e0 = exp2f(accS[s][n][0]);
        float e1 = exp2f(accS[s][n][1]);
        float e2 = exp2f(accS[s][n][2]);
        float e3 = exp2f(accS[s][n][3]);
        rsum[s] += (e0 + e1) + (e2 + e3);
        f16x2 lo = __builtin_bit_cast(f16x2, __builtin_amdgcn_cvt_pkrtz(e0, e1));
        f16x2 hi = __builtin_bit_cast(f16x2, __builtin_amdgcn_cvt_pkrtz(e2, e3));
        pB[s][n] = f16x4{lo[0], lo[1], hi[0], hi[1]};
      }

    // O^T += V^T·P : A = V^T-frag (row=d=l15, k=key=quad*4+j) via ds_read_b64
#pragma unroll
    for (int n = 0; n < 4; ++n) {
#pragma unroll
      for (int n2 = 0; n2 < 4; ++n2) {
        f16x4 vA = *(const f16x4*)(Vsh + (n2 * 16 + l15) * 72 + n * 16 + quad * 4);
#pragma unroll
        for (int s = 0; s < 2; ++s)
          accO[n2][s] = __builtin_amdgcn_mfma_f32_16x16x16f16(vA, pB[s][n], accO[n2][s], 0, 0, 0);
      }
    }
  }

  // rsum: per-lane q=l15; reduce across quads only
#pragma unroll
  for (int s = 0; s < 2; ++s) {
    float t = rsum[s];
    t += __shfl_xor(t, 16, 64);
    t += __shfl_xor(t, 32, 64);
    rsum[s] = t;
  }

  if (lsplit) {
    const int slot = (part * BATCH + b) * NH + h;
    const size_t ob = (size_t)slot * TSEQ * HD;
#pragma unroll
    for (int s = 0; s < 2; ++s) {
      const int t = q0 + s * 16 + l15;
#pragma unroll
      for (int n2 = 0; n2 < 4; ++n2) {
        const int d0 = n2 * 16 + quad * 4;
        unsigned short o[4];
#pragma unroll
        for (int r = 0; r < 4; ++r) o[r] = f2bf(accO[n2][s][r]);
        *(s16x4*)(Opart + ob + (size_t)t * HD + d0) = *(const s16x4*)o;
      }
    }
    if (quad == 0) {
      const size_t rb = (size_t)slot * TSEQ;
#pragma unroll
      for (int s = 0; s < 2; ++s)
        rsumP[rb + q0 + s * 16 + l15] = rsum[s];
    }
  } else {
#pragma unroll
    for (int s = 0; s < 2; ++s) {
      const int t = q0 + s * 16 + l15;
      const float inv = 1.f / rsum[s];
#pragma unroll
      for (int n2 = 0; n2 < 4; ++n2) {
        const int d0 = n2 * 16 + quad * 4;
        unsigned short o[4];
#pragma unroll
        for (int r = 0; r < 4; ++r) o[r] = f2bf(accO[n2][s][r] * inv);
        *(s16x4*)(ctx + ((size_t)(b * TSEQ + t)) * HID + h * HD + d0) = *(const s16x4*)o;
      }
    }
  }
}

// ---------------- combine K-split parts: ctx = sum(O_p)/sum(r_p), bf16 ----------------
__global__ __launch_bounds__(256) void combine_k(
    const unsigned short* __restrict__ Opart, const float* __restrict__ rsumP,
    unsigned short* __restrict__ ctx, int nparts) {
  const int gtid = blockIdx.x * 256 + threadIdx.x;  // 524288 total
  const int d = (gtid & 7) * 8;
  const int rem = gtid >> 3;
  const int t = rem & 2047;
  const int bh = rem >> 11;          // b*NH + h  (0..31)
  float acc[8] = {0, 0, 0, 0, 0, 0, 0, 0};
  float rs = 0.f;
  for (int p = 0; p < nparts; ++p) {
    const int slot = p * 32 + bh;
    s16x8 a = *(const s16x8*)(Opart + ((size_t)slot * TSEQ + t) * HD + d);
#pragma unroll
    for (int j = 0; j < 8; ++j) acc[j] += bf2f(((const unsigned short*)&a)[j]);
    rs += rsumP[(size_t)slot * TSEQ + t];
  }
  const float inv = 1.f / rs;
  unsigned short o[8];
#pragma unroll
  for (int j = 0; j < 8; ++j) o[j] = f2bf(acc[j] * inv);
  const int b = bh >> 4, h = bh & 15;
  *(s16x8*)(ctx + ((size_t)(b * TSEQ + t)) * HID + h * HD + d) = *(const s16x8*)o;
}

// ---------------- In-place LayerNorm over rows of 1024 ----------------
__global__ __launch_bounds__(256) void ln_k(float* __restrict__ io,
                                            const float* __restrict__ gamma,
                                            const float* __restrict__ beta) {
  const int row = blockIdx.x, tid = threadIdx.x;
  float x[4]; float s = 0.f, s2 = 0.f;
#pragma unroll
  for (int i = 0; i < 4; ++i) {
    x[i] = io[(size_t)row * HID + tid + i * 256];
    s += x[i]; s2 += x[i] * x[i];
  }
#pragma unroll
  for (int off = 1; off < 64; off <<= 1) {
    s  += __shfl_xor(s, off, 64);
    s2 += __shfl_xor(s2, off, 64);
  }
  __shared__ float red[8];
  const int wave = tid >> 6;
  if ((tid & 63) == 0) { red[wave] = s; red[wave + 4] = s2; }
  __syncthreads();
  s  = red[0] + red[1] + red[2] + red[3];
  s2 = red[4] + red[5] + red[6] + red[7];
  const float mean = s * (1.f / HID);
  const float var  = s2 * (1.f / HID) - mean * mean;
  const float rstd = rsqrtf(var + 1e-6f);
#pragma unroll
  for (int i = 0; i < 4; ++i) {
    const int col = tid + i * 256;
    io[(size_t)row * HID + col] = (x[i] - mean) * rstd * gamma[col] + beta[col];
  }
}

extern "C" void kernel_launch(void* const* d_in, const int* in_sizes, int n_in,
                              void* d_out, int out_size, void* d_ws, size_t ws_size,
                              hipStream_t stream) {
  const float* h    = (const float*)d_in[0];
  const float* Wq   = (const float*)d_in[1];
  const float* bq   = (const float*)d_in[2];
  const float* Wk   = (const float*)d_in[3];
  const float* bk   = (const float*)d_in[4];
  const float* Wv   = (const float*)d_in[5];
  const float* bv   = (const float*)d_in[6];
  const float* Wo   = (const float*)d_in[7];
  const float* bo   = (const float*)d_in[8];
  const float* gamma = (const float*)d_in[9];
  const float* beta  = (const float*)d_in[10];
  float* out = (float*)d_out;

  unsigned short* hb   = (unsigned short*)d_ws;   // bf16 h; dead after gemm_qkv -> reused as ctx
  unsigned short* wqb  = hb  + 4194304;           // 4 weights contiguous
  unsigned short* wkb  = wqb + 1048576;
  unsigned short* wvb  = wkb + 1048576;
  unsigned short* wob  = wvb + 1048576;
  unsigned short* qb   = wob + 1048576;           // bf16 [B,NH,T,D]
  unsigned short* kb   = qb  + 4194304;
  unsigned short* vtf  = kb  + 4194304;           // f16 [B,NH,D,T], written by gemm_qkv directly
  unsigned short* Opart = vtf + 4194304;          // bf16 partials (up to 4 parts x 8 MiB)
  unsigned short* ctxb = hb;                      // ctx aliases dead hb

  const size_t base = (size_t)(vtf + 4194304 - hb) * 2;  // bytes before Opart (40 MiB)
  int lsplit = 0;
  if (ws_size >= base + 4u * 8388608 + 4u * 262144) lsplit = 2;       // ~73 MiB
  else if (ws_size >= base + 2u * 8388608 + 2u * 262144) lsplit = 1;  // ~57 MiB
  const int nparts = 1 << lsplit;
  float* rsumP = (float*)(Opart + (size_t)nparts * 4194304);

  cast_all_k<<<8192, 256, 0, stream>>>(h, Wq, Wk, Wv, Wo, hb, wqb);
  gemm_qkv<<<dim3(8, 32, 3), 256, 0, stream>>>(hb, wqb, wkb, wvb, bq, bk, bv, qb, kb, vtf);
  attn_k<<<dim3(TSEQ / 128, NH, BATCH << lsplit), 256, 0, stream>>>(
      qb, kb, vtf, ctxb, Opart, rsumP, lsplit, 32 >> lsplit);
  if (lsplit)
    combine_k<<<2048, 256, 0, stream>>>(Opart, rsumP, ctxb, nparts);
  gemm_out<<<dim3(16, 32), 256, 0, stream>>>(ctxb, wob, bo, h, out);
  ln_k<<<4096, 256, 0, stream>>>(out, gamma, beta);
}

// Round 10
// 226.952 us; speedup vs baseline: 1.0765x; 1.0765x over previous
//
#include <hip/hip_runtime.h>
#include <hip/hip_bf16.h>

#define NH   16
#define HD   64
#define HID  1024
#define TSEQ 2048
#define BATCH 2
#define KSCALE 0.18033688011112042f   // 0.125 * log2(e), folded into Wk/bk

typedef __attribute__((ext_vector_type(4))) float f32x4;
typedef __attribute__((ext_vector_type(8))) short s16x8;
typedef __attribute__((ext_vector_type(4))) short s16x4;
typedef __attribute__((ext_vector_type(8))) _Float16 f16x8;
typedef __attribute__((ext_vector_type(4))) _Float16 f16x4;
typedef __attribute__((ext_vector_type(2))) _Float16 f16x2;

__device__ __forceinline__ unsigned short f2bf(float f) {
  union { float f; unsigned int u; } v; v.f = f;
  unsigned int r = v.u + 0x7fffu + ((v.u >> 16) & 1u);
  return (unsigned short)(r >> 16);
}
__device__ __forceinline__ float bf2f(unsigned short b) {
  union { unsigned int u; float f; } v; v.u = ((unsigned int)b) << 16; return v.f;
}

__device__ __forceinline__ void async_cp16(const unsigned short* g, unsigned short* l) {
  __builtin_amdgcn_global_load_lds(
      (const __attribute__((address_space(1))) unsigned int*)g,
      (__attribute__((address_space(3))) unsigned int*)l, 16, 0, 0);
}

// ---------------- one cast kernel: h + all 4 weights (Wk pre-scaled) ----------------
__global__ __launch_bounds__(256) void cast_all_k(
    const float* __restrict__ h,
    const float* __restrict__ w0, const float* __restrict__ w1,
    const float* __restrict__ w2, const float* __restrict__ w3,
    unsigned short* __restrict__ hb, unsigned short* __restrict__ wbase) {
  int i = blockIdx.x * 256 + threadIdx.x;  // 2097152 float4 total
  const float* src; unsigned short* dst; int idx; float sc = 1.f;
  if (i < 1048576) { src = h; dst = hb; idx = i; }
  else {
    int idx4 = i - 1048576;
    int w = idx4 >> 18;
    idx = idx4 & 262143;
    src = (w == 0) ? w0 : (w == 1) ? w1 : (w == 2) ? w2 : w3;
    dst = wbase + (size_t)(idx4 - idx) * 4;   // contiguous weight region
    if (w == 1) sc = KSCALE;
  }
  float4 v = ((const float4*)src)[idx];
  ushort4 o;
  o.x = f2bf(v.x * sc); o.y = f2bf(v.y * sc); o.z = f2bf(v.z * sc); o.w = f2bf(v.w * sc);
  ((ushort4*)dst)[idx] = o;
}

// ---------------- GEMM core: C[128x128] += A[128xK] * B[128xK]^T ----------------
__device__ __forceinline__ void gemm_core(const unsigned short* __restrict__ Ag,
                                          const unsigned short* __restrict__ Bg,
                                          unsigned short* Ash, unsigned short* Bsh,
                                          f32x4 acc[4][4]) {
  const int tid  = threadIdx.x;
  const int lane = tid & 63;
  const int wave = tid >> 6;
  const int l15  = lane & 15;
  const int quad = lane >> 4;
  const int wm   = (wave >> 1) * 64;
  const int wn   = (wave & 1) * 64;
  const int idx0 = tid * 8;
  const int idx1 = idx0 + 2048;
  const int r0 = idx0 >> 5, c0 = idx0 & 31;
  const int r1 = idx1 >> 5, c1 = idx1 & 31;
#pragma unroll
  for (int i = 0; i < 4; ++i)
#pragma unroll
    for (int j = 0; j < 4; ++j) acc[i][j] = f32x4{0.f, 0.f, 0.f, 0.f};

  for (int k0 = 0; k0 < HID; k0 += 32) {
    __syncthreads();
    async_cp16(Ag + r0 * HID + k0 + c0, Ash + idx0);
    async_cp16(Ag + r1 * HID + k0 + c1, Ash + idx1);
    async_cp16(Bg + r0 * HID + k0 + c0, Bsh + idx0);
    async_cp16(Bg + r1 * HID + k0 + c1, Bsh + idx1);
    __syncthreads();
    s16x8 af[4], bfr[4];
#pragma unroll
    for (int i = 0; i < 4; ++i)
      af[i] = *(const s16x8*)(Ash + (wm + i * 16 + l15) * 32 + quad * 8);
#pragma unroll
    for (int j = 0; j < 4; ++j)
      bfr[j] = *(const s16x8*)(Bsh + (wn + j * 16 + l15) * 32 + quad * 8);
#pragma unroll
    for (int i = 0; i < 4; ++i)
#pragma unroll
      for (int j = 0; j < 4; ++j)
        acc[i][j] = __builtin_amdgcn_mfma_f32_16x16x32_bf16(af[i], bfr[j], acc[i][j], 0, 0, 0);
  }
}

// ---------------- QKV projection; V written f16-transposed [B,NH,D,T] ----------------
__global__ __launch_bounds__(256) void gemm_qkv(
    const unsigned short* __restrict__ hb,
    const unsigned short* __restrict__ wq, const unsigned short* __restrict__ wk,
    const unsigned short* __restrict__ wv,
    const float* __restrict__ bq, const float* __restrict__ bk, const float* __restrict__ bv,
    unsigned short* __restrict__ qo, unsigned short* __restrict__ ko,
    unsigned short* __restrict__ vto) {
  __shared__ unsigned short Ash[128 * 32];
  __shared__ unsigned short Bsh[128 * 32];
  const unsigned short* Bw; const float* bias; float bsc = 1.f;
  if (blockIdx.z == 0)      { Bw = wq; bias = bq; }
  else if (blockIdx.z == 1) { Bw = wk; bias = bk; bsc = KSCALE; }
  else                      { Bw = wv; bias = bv; }
  const int bm = blockIdx.y * 128, bn = blockIdx.x * 128;
  f32x4 acc[4][4];
  gemm_core(hb + (size_t)bm * HID, Bw + (size_t)bn * HID, Ash, Bsh, acc);

  const int tid = threadIdx.x, lane = tid & 63, wave = tid >> 6;
  const int l15 = lane & 15, quad = lane >> 4;
  const int wm = (wave >> 1) * 64, wn = (wave & 1) * 64;
  if (blockIdx.z == 2) {
    // V: f16, transposed to [B,NH,D,T]; 4 consecutive t per lane = 8B store
#pragma unroll
    for (int j = 0; j < 4; ++j) {
      const int col = bn + wn + j * 16 + l15;
      const float bb = bias[col];
      const int head = col >> 6, d = col & 63;
#pragma unroll
      for (int i = 0; i < 4; ++i) {
        const int row0 = bm + wm + i * 16 + quad * 4;
        const int bI = row0 >> 11, t0 = row0 & 2047;
        unsigned short o[4];
#pragma unroll
        for (int r = 0; r < 4; ++r) {
          _Float16 hv = (_Float16)(acc[i][j][r] + bb);
          o[r] = __builtin_bit_cast(unsigned short, hv);
        }
        *(s16x4*)(vto + ((size_t)((bI * NH + head) * HD + d)) * TSEQ + t0) = *(const s16x4*)o;
      }
    }
  } else {
    unsigned short* outp = (blockIdx.z == 0) ? qo : ko;
#pragma unroll
    for (int j = 0; j < 4; ++j) {
      const int col = bn + wn + j * 16 + l15;
      const float bb = bias[col] * bsc;
      const int head = col >> 6, d = col & 63;
#pragma unroll
      for (int i = 0; i < 4; ++i) {
#pragma unroll
        for (int r = 0; r < 4; ++r) {
          const int row = bm + wm + i * 16 + quad * 4 + r;  // row = b*T + t
          const int bI = row >> 11, t = row & 2047;
          outp[(((size_t)(bI * NH + head) * TSEQ) + t) * HD + d] = f2bf(acc[i][j][r] + bb);
        }
      }
    }
  }
}

// ---------------- Output projection, 128x64 tiles: out = ctx @ Wo^T + bo + h ----------------
__global__ __launch_bounds__(256) void gemm_out(
    const unsigned short* __restrict__ ctx, const unsigned short* __restrict__ wo,
    const float* __restrict__ bo, const float* __restrict__ hres,
    float* __restrict__ outf) {
  __shared__ unsigned short Ash[128 * 32];
  __shared__ unsigned short Bsh[64 * 32];
  const int tid = threadIdx.x, lane = tid & 63, wave = tid >> 6;
  const int l15 = lane & 15, quad = lane >> 4;
  const int wm = (wave >> 1) * 64, wn = (wave & 1) * 32;
  const int bm = blockIdx.y * 128, bn = blockIdx.x * 64;
  const unsigned short* Ag = ctx + (size_t)bm * HID;
  const unsigned short* Bg = wo + (size_t)bn * HID;
  const int idx0 = tid * 8, idx1 = idx0 + 2048;
  const int r0 = idx0 >> 5, c0 = idx0 & 31;
  const int r1 = idx1 >> 5, c1 = idx1 & 31;
  f32x4 acc[4][2];
#pragma unroll
  for (int i = 0; i < 4; ++i)
#pragma unroll
    for (int j = 0; j < 2; ++j) acc[i][j] = f32x4{0.f, 0.f, 0.f, 0.f};

  for (int k0 = 0; k0 < HID; k0 += 32) {
    __syncthreads();
    async_cp16(Ag + r0 * HID + k0 + c0, Ash + idx0);
    async_cp16(Ag + r1 * HID + k0 + c1, Ash + idx1);
    async_cp16(Bg + r0 * HID + k0 + c0, Bsh + idx0);
    __syncthreads();
    s16x8 af[4], bfr[2];
#pragma unroll
    for (int i = 0; i < 4; ++i)
      af[i] = *(const s16x8*)(Ash + (wm + i * 16 + l15) * 32 + quad * 8);
#pragma unroll
    for (int j = 0; j < 2; ++j)
      bfr[j] = *(const s16x8*)(Bsh + (wn + j * 16 + l15) * 32 + quad * 8);
#pragma unroll
    for (int i = 0; i < 4; ++i)
#pragma unroll
      for (int j = 0; j < 2; ++j)
        acc[i][j] = __builtin_amdgcn_mfma_f32_16x16x32_bf16(af[i], bfr[j], acc[i][j], 0, 0, 0);
  }
#pragma unroll
  for (int j = 0; j < 2; ++j) {
    const int col = bn + wn + j * 16 + l15;
    const float bb = bo[col];
#pragma unroll
    for (int i = 0; i < 4; ++i) {
#pragma unroll
      for (int r = 0; r < 4; ++r) {
        const int row = bm + wm + i * 16 + quad * 4 + r;
        const size_t off = (size_t)row * HID + col;
        outf[off] = acc[i][j][r] + bb + hres[off];
      }
    }
  }
}

// ---------------- Flash attention: S^T formulation, K-split by 1/2 ----------------
// Q bf16, K bf16 (pre-scaled), V f16 [B,NH,D,T].
// blockIdx.z = b << lsplit | part; each block handles ntiles = 32>>lsplit K-tiles.
__global__ __launch_bounds__(256, 2) void attn_k(
    const unsigned short* __restrict__ qb, const unsigned short* __restrict__ kb,
    const unsigned short* __restrict__ vt, unsigned short* __restrict__ ctx,
    unsigned short* __restrict__ Opart, float* __restrict__ rsumP,
    int lsplit, int ntiles) {
  __shared__ unsigned short Ksh[64 * 72];   // bf16 [key][d]
  __shared__ unsigned short Vsh[64 * 72];   // f16  [d][key]

  const int tid = threadIdx.x, lane = tid & 63, wave = tid >> 6;
  const int l15 = lane & 15, quad = lane >> 4;
  const int z = blockIdx.z;
  const int b = z >> lsplit;
  const int part = z & ((1 << lsplit) - 1);
  const int h = blockIdx.y, qt = blockIdx.x;
  const size_t ho = ((size_t)(b * NH + h)) * TSEQ * HD;
  const unsigned short* Qh = qb + ho;
  const unsigned short* Kh = kb + ho;
  const unsigned short* Vh = vt + ho;
  const int q0 = qt * 128 + wave * 32;
  const int kt0 = part * ntiles;

  // Q fragments (B-operand of S^T): col q=l15, k over d
  s16x8 qf[2][2];
#pragma unroll
  for (int s = 0; s < 2; ++s)
#pragma unroll
    for (int ks = 0; ks < 2; ++ks)
      qf[s][ks] = *(const s16x8*)(Qh + (size_t)(q0 + s * 16 + l15) * HD + ks * 32 + quad * 8);

  f32x4 accO[4][2];   // O^T: [d-strip n2][q-col s], lane=(d=quad*4+r, q=l15)
  float rsum[2];      // per-lane: q = s*16 + l15
#pragma unroll
  for (int n2 = 0; n2 < 4; ++n2)
#pragma unroll
    for (int s = 0; s < 2; ++s) accO[n2][s] = f32x4{0.f, 0.f, 0.f, 0.f};
  rsum[0] = rsum[1] = 0.f;

  const int sr = tid >> 3, sc = (tid & 7) * 8;
  s16x8 kreg[2], vreg[2];
#pragma unroll
  for (int hf = 0; hf < 2; ++hf) {
    kreg[hf] = *(const s16x8*)(Kh + (size_t)(kt0 * 64 + sr + hf * 32) * HD + sc);
    vreg[hf] = *(const s16x8*)(Vh + (size_t)(sr + hf * 32) * TSEQ + kt0 * 64 + sc);
  }

  for (int kt = 0; kt < ntiles; ++kt) {
    __syncthreads();
#pragma unroll
    for (int hf = 0; hf < 2; ++hf) {
      *(s16x8*)(Ksh + (sr + hf * 32) * 72 + sc) = kreg[hf];
      *(s16x8*)(Vsh + (sr + hf * 32) * 72 + sc) = vreg[hf];
    }
    __syncthreads();
    if (kt + 1 < ntiles) {
      const int k0n = (kt0 + kt + 1) * 64;
#pragma unroll
      for (int hf = 0; hf < 2; ++hf) {
        kreg[hf] = *(const s16x8*)(Kh + (size_t)(k0n + sr + hf * 32) * HD + sc);
        vreg[hf] = *(const s16x8*)(Vh + (size_t)(sr + hf * 32) * TSEQ + k0n + sc);
      }
    }

    // S^T = K·Q^T: A = K-frag (row=key), B = Q-frag (col=q)
    f32x4 accS[2][4];   // [q-col s][key-strip n]
#pragma unroll
    for (int s = 0; s < 2; ++s)
#pragma unroll
      for (int n = 0; n < 4; ++n) accS[s][n] = f32x4{0.f, 0.f, 0.f, 0.f};
#pragma unroll
    for (int ks = 0; ks < 2; ++ks) {
#pragma unroll
      for (int n = 0; n < 4; ++n) {
        s16x8 kf = *(const s16x8*)(Ksh + (n * 16 + l15) * 72 + ks * 32 + quad * 8);
#pragma unroll
        for (int s = 0; s < 2; ++s)
          accS[s][n] = __builtin_amdgcn_mfma_f32_16x16x32_bf16(kf, qf[s][ks], accS[s][n], 0, 0, 0);
      }
    }

    // exp via raw v_exp_f32 (inputs bounded; libm exp2f's range-fixup is the
    // VALU bottleneck measured in R9: ~350 insts/tile -> ~130)
    f16x4 pB[2][4];
#pragma unroll
    for (int s = 0; s < 2; ++s)
#pragma unroll
      for (int n = 0; n < 4; ++n) {
        float e0 = __builtin_amdgcn_exp2f(accS[s][n][0]);
        float e1 = __builtin_amdgcn_exp2f(accS[s][n][1]);
        float e2 = __builtin_amdgcn_exp2f(accS[s][n][2]);
        float e3 = __builtin_amdgcn_exp2f(accS[s][n][3]);
        rsum[s] += (e0 + e1) + (e2 + e3);
        f16x2 lo = __builtin_bit_cast(f16x2, __builtin_amdgcn_cvt_pkrtz(e0, e1));
        f16x2 hi = __builtin_bit_cast(f16x2, __builtin_amdgcn_cvt_pkrtz(e2, e3));
        pB[s][n] = f16x4{lo[0], lo[1], hi[0], hi[1]};
      }

    // O^T += V^T·P : A = V^T-frag (row=d=l15, k=key=quad*4+j) via ds_read_b64
#pragma unroll
    for (int n = 0; n < 4; ++n) {
#pragma unroll
      for (int n2 = 0; n2 < 4; ++n2) {
        f16x4 vA = *(const f16x4*)(Vsh + (n2 * 16 + l15) * 72 + n * 16 + quad * 4);
#pragma unroll
        for (int s = 0; s < 2; ++s)
          accO[n2][s] = __builtin_amdgcn_mfma_f32_16x16x16f16(vA, pB[s][n], accO[n2][s], 0, 0, 0);
      }
    }
  }

  // rsum: per-lane q=l15; reduce across quads only
#pragma unroll
  for (int s = 0; s < 2; ++s) {
    float t = rsum[s];
    t += __shfl_xor(t, 16, 64);
    t += __shfl_xor(t, 32, 64);
    rsum[s] = t;
  }

  if (lsplit) {
    const int slot = (part * BATCH + b) * NH + h;
    const size_t ob = (size_t)slot * TSEQ * HD;
#pragma unroll
    for (int s = 0; s < 2; ++s) {
      const int t = q0 + s * 16 + l15;
#pragma unroll
      for (int n2 = 0; n2 < 4; ++n2) {
        const int d0 = n2 * 16 + quad * 4;
        unsigned short o[4];
#pragma unroll
        for (int r = 0; r < 4; ++r) o[r] = f2bf(accO[n2][s][r]);
        *(s16x4*)(Opart + ob + (size_t)t * HD + d0) = *(const s16x4*)o;
      }
    }
    if (quad == 0) {
      const size_t rb = (size_t)slot * TSEQ;
#pragma unroll
      for (int s = 0; s < 2; ++s)
        rsumP[rb + q0 + s * 16 + l15] = rsum[s];
    }
  } else {
#pragma unroll
    for (int s = 0; s < 2; ++s) {
      const int t = q0 + s * 16 + l15;
      const float inv = 1.f / rsum[s];
#pragma unroll
      for (int n2 = 0; n2 < 4; ++n2) {
        const int d0 = n2 * 16 + quad * 4;
        unsigned short o[4];
#pragma unroll
        for (int r = 0; r < 4; ++r) o[r] = f2bf(accO[n2][s][r] * inv);
        *(s16x4*)(ctx + ((size_t)(b * TSEQ + t)) * HID + h * HD + d0) = *(const s16x4*)o;
      }
    }
  }
}

// ---------------- combine K-split parts: ctx = sum(O_p)/sum(r_p), bf16 ----------------
__global__ __launch_bounds__(256) void combine_k(
    const unsigned short* __restrict__ Opart, const float* __restrict__ rsumP,
    unsigned short* __restrict__ ctx, int nparts) {
  const int gtid = blockIdx.x * 256 + threadIdx.x;  // 524288 total
  const int d = (gtid & 7) * 8;
  const int rem = gtid >> 3;
  const int t = rem & 2047;
  const int bh = rem >> 11;          // b*NH + h  (0..31)
  float acc[8] = {0, 0, 0, 0, 0, 0, 0, 0};
  float rs = 0.f;
  for (int p = 0; p < nparts; ++p) {
    const int slot = p * 32 + bh;
    s16x8 a = *(const s16x8*)(Opart + ((size_t)slot * TSEQ + t) * HD + d);
#pragma unroll
    for (int j = 0; j < 8; ++j) acc[j] += bf2f(((const unsigned short*)&a)[j]);
    rs += rsumP[(size_t)slot * TSEQ + t];
  }
  const float inv = 1.f / rs;
  unsigned short o[8];
#pragma unroll
  for (int j = 0; j < 8; ++j) o[j] = f2bf(acc[j] * inv);
  const int b = bh >> 4, h = bh & 15;
  *(s16x8*)(ctx + ((size_t)(b * TSEQ + t)) * HID + h * HD + d) = *(const s16x8*)o;
}

// ---------------- In-place LayerNorm over rows of 1024 ----------------
__global__ __launch_bounds__(256) void ln_k(float* __restrict__ io,
                                            const float* __restrict__ gamma,
                                            const float* __restrict__ beta) {
  const int row = blockIdx.x, tid = threadIdx.x;
  float x[4]; float s = 0.f, s2 = 0.f;
#pragma unroll
  for (int i = 0; i < 4; ++i) {
    x[i] = io[(size_t)row * HID + tid + i * 256];
    s += x[i]; s2 += x[i] * x[i];
  }
#pragma unroll
  for (int off = 1; off < 64; off <<= 1) {
    s  += __shfl_xor(s, off, 64);
    s2 += __shfl_xor(s2, off, 64);
  }
  __shared__ float red[8];
  const int wave = tid >> 6;
  if ((tid & 63) == 0) { red[wave] = s; red[wave + 4] = s2; }
  __syncthreads();
  s  = red[0] + red[1] + red[2] + red[3];
  s2 = red[4] + red[5] + red[6] + red[7];
  const float mean = s * (1.f / HID);
  const float var  = s2 * (1.f / HID) - mean * mean;
  const float rstd = rsqrtf(var + 1e-6f);
#pragma unroll
  for (int i = 0; i < 4; ++i) {
    const int col = tid + i * 256;
    io[(size_t)row * HID + col] = (x[i] - mean) * rstd * gamma[col] + beta[col];
  }
}

extern "C" void kernel_launch(void* const* d_in, const int* in_sizes, int n_in,
                              void* d_out, int out_size, void* d_ws, size_t ws_size,
                              hipStream_t stream) {
  const float* h    = (const float*)d_in[0];
  const float* Wq   = (const float*)d_in[1];
  const float* bq   = (const float*)d_in[2];
  const float* Wk   = (const float*)d_in[3];
  const float* bk   = (const float*)d_in[4];
  const float* Wv   = (const float*)d_in[5];
  const float* bv   = (const float*)d_in[6];
  const float* Wo   = (const float*)d_in[7];
  const float* bo   = (const float*)d_in[8];
  const float* gamma = (const float*)d_in[9];
  const float* beta  = (const float*)d_in[10];
  float* out = (float*)d_out;

  unsigned short* hb   = (unsigned short*)d_ws;   // bf16 h; dead after gemm_qkv -> reused as ctx
  unsigned short* wqb  = hb  + 4194304;           // 4 weights contiguous
  unsigned short* wkb  = wqb + 1048576;
  unsigned short* wvb  = wkb + 1048576;
  unsigned short* wob  = wvb + 1048576;
  unsigned short* qb   = wob + 1048576;           // bf16 [B,NH,T,D]
  unsigned short* kb   = qb  + 4194304;
  unsigned short* vtf  = kb  + 4194304;           // f16 [B,NH,D,T], written by gemm_qkv directly
  unsigned short* Opart = vtf + 4194304;          // bf16 partials (2 parts x 8 MiB)
  unsigned short* ctxb = hb;                      // ctx aliases dead hb

  const size_t base = (size_t)(vtf + 4194304 - hb) * 2;  // bytes before Opart (40 MiB)
  int lsplit = 0;
  if (ws_size >= base + 2u * 8388608 + 2u * 262144) lsplit = 1;  // ~57 MiB
  const int nparts = 1 << lsplit;
  float* rsumP = (float*)(Opart + (size_t)nparts * 4194304);

  cast_all_k<<<8192, 256, 0, stream>>>(h, Wq, Wk, Wv, Wo, hb, wqb);
  gemm_qkv<<<dim3(8, 32, 3), 256, 0, stream>>>(hb, wqb, wkb, wvb, bq, bk, bv, qb, kb, vtf);
  attn_k<<<dim3(TSEQ / 128, NH, BATCH << lsplit), 256, 0, stream>>>(
      qb, kb, vtf, ctxb, Opart, rsumP, lsplit, 32 >> lsplit);
  if (lsplit)
    combine_k<<<2048, 256, 0, stream>>>(Opart, rsumP, ctxb, nparts);
  gemm_out<<<dim3(16, 32), 256, 0, stream>>>(ctxb, wob, bo, h, out);
  ln_k<<<4096, 256, 0, stream>>>(out, gamma, beta);
}

// Round 11
// 226.099 us; speedup vs baseline: 1.0806x; 1.0038x over previous
//
#include <hip/hip_runtime.h>
#include <hip/hip_bf16.h>

#define NH   16
#define HD   64
#define HID  1024
#define TSEQ 2048
#define BATCH 2
#define KSCALE 0.18033688011112042f   // 0.125 * log2(e), folded into Wk/bk

typedef __attribute__((ext_vector_type(4))) float f32x4;
typedef __attribute__((ext_vector_type(8))) short s16x8;
typedef __attribute__((ext_vector_type(4))) short s16x4;
typedef __attribute__((ext_vector_type(8))) _Float16 f16x8;
typedef __attribute__((ext_vector_type(4))) _Float16 f16x4;
typedef __attribute__((ext_vector_type(2))) _Float16 f16x2;

__device__ __forceinline__ unsigned short f2bf(float f) {
  union { float f; unsigned int u; } v; v.f = f;
  unsigned int r = v.u + 0x7fffu + ((v.u >> 16) & 1u);
  return (unsigned short)(r >> 16);
}
__device__ __forceinline__ float bf2f(unsigned short b) {
  union { unsigned int u; float f; } v; v.u = ((unsigned int)b) << 16; return v.f;
}

__device__ __forceinline__ void async_cp16(const unsigned short* g, unsigned short* l) {
  __builtin_amdgcn_global_load_lds(
      (const __attribute__((address_space(1))) unsigned int*)g,
      (__attribute__((address_space(3))) unsigned int*)l, 16, 0, 0);
}

// ---------------- one cast kernel: h + all 4 weights (Wk pre-scaled) ----------------
__global__ __launch_bounds__(256) void cast_all_k(
    const float* __restrict__ h,
    const float* __restrict__ w0, const float* __restrict__ w1,
    const float* __restrict__ w2, const float* __restrict__ w3,
    unsigned short* __restrict__ hb, unsigned short* __restrict__ wbase) {
  int i = blockIdx.x * 256 + threadIdx.x;  // 2097152 float4 total
  const float* src; unsigned short* dst; int idx; float sc = 1.f;
  if (i < 1048576) { src = h; dst = hb; idx = i; }
  else {
    int idx4 = i - 1048576;
    int w = idx4 >> 18;
    idx = idx4 & 262143;
    src = (w == 0) ? w0 : (w == 1) ? w1 : (w == 2) ? w2 : w3;
    dst = wbase + (size_t)(idx4 - idx) * 4;   // contiguous weight region
    if (w == 1) sc = KSCALE;
  }
  float4 v = ((const float4*)src)[idx];
  ushort4 o;
  o.x = f2bf(v.x * sc); o.y = f2bf(v.y * sc); o.z = f2bf(v.z * sc); o.w = f2bf(v.w * sc);
  ((ushort4*)dst)[idx] = o;
}

// ---------------- QKV projection, 128x64 tiles; V written f16-transposed ----------------
// grid (16, 32, 3): bn = x*64, bm = y*128. 6 blocks/CU to hide barrier drains.
__global__ __launch_bounds__(256) void gemm_qkv(
    const unsigned short* __restrict__ hb,
    const unsigned short* __restrict__ wq, const unsigned short* __restrict__ wk,
    const unsigned short* __restrict__ wv,
    const float* __restrict__ bq, const float* __restrict__ bk, const float* __restrict__ bv,
    unsigned short* __restrict__ qo, unsigned short* __restrict__ ko,
    unsigned short* __restrict__ vto) {
  __shared__ unsigned short Ash[128 * 32];
  __shared__ unsigned short Bsh[64 * 32];
  const unsigned short* Bw; const float* bias; float bsc = 1.f;
  if (blockIdx.z == 0)      { Bw = wq; bias = bq; }
  else if (blockIdx.z == 1) { Bw = wk; bias = bk; bsc = KSCALE; }
  else                      { Bw = wv; bias = bv; }
  const int tid = threadIdx.x, lane = tid & 63, wave = tid >> 6;
  const int l15 = lane & 15, quad = lane >> 4;
  const int wm = (wave >> 1) * 64, wn = (wave & 1) * 32;
  const int bm = blockIdx.y * 128, bn = blockIdx.x * 64;
  const unsigned short* Ag = hb + (size_t)bm * HID;
  const unsigned short* Bg = Bw + (size_t)bn * HID;
  const int idx0 = tid * 8, idx1 = idx0 + 2048;
  const int r0 = idx0 >> 5, c0 = idx0 & 31;
  const int r1 = idx1 >> 5, c1 = idx1 & 31;
  f32x4 acc[4][2];
#pragma unroll
  for (int i = 0; i < 4; ++i)
#pragma unroll
    for (int j = 0; j < 2; ++j) acc[i][j] = f32x4{0.f, 0.f, 0.f, 0.f};

  for (int k0 = 0; k0 < HID; k0 += 32) {
    __syncthreads();
    async_cp16(Ag + r0 * HID + k0 + c0, Ash + idx0);
    async_cp16(Ag + r1 * HID + k0 + c1, Ash + idx1);
    async_cp16(Bg + r0 * HID + k0 + c0, Bsh + idx0);
    __syncthreads();
    s16x8 af[4], bfr[2];
#pragma unroll
    for (int i = 0; i < 4; ++i)
      af[i] = *(const s16x8*)(Ash + (wm + i * 16 + l15) * 32 + quad * 8);
#pragma unroll
    for (int j = 0; j < 2; ++j)
      bfr[j] = *(const s16x8*)(Bsh + (wn + j * 16 + l15) * 32 + quad * 8);
#pragma unroll
    for (int i = 0; i < 4; ++i)
#pragma unroll
      for (int j = 0; j < 2; ++j)
        acc[i][j] = __builtin_amdgcn_mfma_f32_16x16x32_bf16(af[i], bfr[j], acc[i][j], 0, 0, 0);
  }

  if (blockIdx.z == 2) {
    // V: f16, transposed to [B,NH,D,T]; 4 consecutive t per lane = 8B store
#pragma unroll
    for (int j = 0; j < 2; ++j) {
      const int col = bn + wn + j * 16 + l15;
      const float bb = bias[col];
      const int head = col >> 6, d = col & 63;
#pragma unroll
      for (int i = 0; i < 4; ++i) {
        const int row0 = bm + wm + i * 16 + quad * 4;
        const int bI = row0 >> 11, t0 = row0 & 2047;
        unsigned short o[4];
#pragma unroll
        for (int r = 0; r < 4; ++r) {
          _Float16 hv = (_Float16)(acc[i][j][r] + bb);
          o[r] = __builtin_bit_cast(unsigned short, hv);
        }
        *(s16x4*)(vto + ((size_t)((bI * NH + head) * HD + d)) * TSEQ + t0) = *(const s16x4*)o;
      }
    }
  } else {
    unsigned short* outp = (blockIdx.z == 0) ? qo : ko;
#pragma unroll
    for (int j = 0; j < 2; ++j) {
      const int col = bn + wn + j * 16 + l15;
      const float bb = bias[col] * bsc;
      const int head = col >> 6, d = col & 63;
#pragma unroll
      for (int i = 0; i < 4; ++i) {
#pragma unroll
        for (int r = 0; r < 4; ++r) {
          const int row = bm + wm + i * 16 + quad * 4 + r;  // row = b*T + t
          const int bI = row >> 11, t = row & 2047;
          outp[(((size_t)(bI * NH + head) * TSEQ) + t) * HD + d] = f2bf(acc[i][j][r] + bb);
        }
      }
    }
  }
}

// ---------------- Output projection, 128x64 tiles: out = ctx @ Wo^T + bo + h ----------------
__global__ __launch_bounds__(256) void gemm_out(
    const unsigned short* __restrict__ ctx, const unsigned short* __restrict__ wo,
    const float* __restrict__ bo, const float* __restrict__ hres,
    float* __restrict__ outf) {
  __shared__ unsigned short Ash[128 * 32];
  __shared__ unsigned short Bsh[64 * 32];
  const int tid = threadIdx.x, lane = tid & 63, wave = tid >> 6;
  const int l15 = lane & 15, quad = lane >> 4;
  const int wm = (wave >> 1) * 64, wn = (wave & 1) * 32;
  const int bm = blockIdx.y * 128, bn = blockIdx.x * 64;
  const unsigned short* Ag = ctx + (size_t)bm * HID;
  const unsigned short* Bg = wo + (size_t)bn * HID;
  const int idx0 = tid * 8, idx1 = idx0 + 2048;
  const int r0 = idx0 >> 5, c0 = idx0 & 31;
  const int r1 = idx1 >> 5, c1 = idx1 & 31;
  f32x4 acc[4][2];
#pragma unroll
  for (int i = 0; i < 4; ++i)
#pragma unroll
    for (int j = 0; j < 2; ++j) acc[i][j] = f32x4{0.f, 0.f, 0.f, 0.f};

  for (int k0 = 0; k0 < HID; k0 += 32) {
    __syncthreads();
    async_cp16(Ag + r0 * HID + k0 + c0, Ash + idx0);
    async_cp16(Ag + r1 * HID + k0 + c1, Ash + idx1);
    async_cp16(Bg + r0 * HID + k0 + c0, Bsh + idx0);
    __syncthreads();
    s16x8 af[4], bfr[2];
#pragma unroll
    for (int i = 0; i < 4; ++i)
      af[i] = *(const s16x8*)(Ash + (wm + i * 16 + l15) * 32 + quad * 8);
#pragma unroll
    for (int j = 0; j < 2; ++j)
      bfr[j] = *(const s16x8*)(Bsh + (wn + j * 16 + l15) * 32 + quad * 8);
#pragma unroll
    for (int i = 0; i < 4; ++i)
#pragma unroll
      for (int j = 0; j < 2; ++j)
        acc[i][j] = __builtin_amdgcn_mfma_f32_16x16x32_bf16(af[i], bfr[j], acc[i][j], 0, 0, 0);
  }
#pragma unroll
  for (int j = 0; j < 2; ++j) {
    const int col = bn + wn + j * 16 + l15;
    const float bb = bo[col];
#pragma unroll
    for (int i = 0; i < 4; ++i) {
#pragma unroll
      for (int r = 0; r < 4; ++r) {
        const int row = bm + wm + i * 16 + quad * 4 + r;
        const size_t off = (size_t)row * HID + col;
        outf[off] = acc[i][j][r] + bb + hres[off];
      }
    }
  }
}

// ---------------- Flash attention: S^T formulation, K-split by 1/2 ----------------
__global__ __launch_bounds__(256, 2) void attn_k(
    const unsigned short* __restrict__ qb, const unsigned short* __restrict__ kb,
    const unsigned short* __restrict__ vt, unsigned short* __restrict__ ctx,
    unsigned short* __restrict__ Opart, float* __restrict__ rsumP,
    int lsplit, int ntiles) {
  __shared__ unsigned short Ksh[64 * 72];   // bf16 [key][d]
  __shared__ unsigned short Vsh[64 * 72];   // f16  [d][key]

  const int tid = threadIdx.x, lane = tid & 63, wave = tid >> 6;
  const int l15 = lane & 15, quad = lane >> 4;
  const int z = blockIdx.z;
  const int b = z >> lsplit;
  const int part = z & ((1 << lsplit) - 1);
  const int h = blockIdx.y, qt = blockIdx.x;
  const size_t ho = ((size_t)(b * NH + h)) * TSEQ * HD;
  const unsigned short* Qh = qb + ho;
  const unsigned short* Kh = kb + ho;
  const unsigned short* Vh = vt + ho;
  const int q0 = qt * 128 + wave * 32;
  const int kt0 = part * ntiles;

  s16x8 qf[2][2];
#pragma unroll
  for (int s = 0; s < 2; ++s)
#pragma unroll
    for (int ks = 0; ks < 2; ++ks)
      qf[s][ks] = *(const s16x8*)(Qh + (size_t)(q0 + s * 16 + l15) * HD + ks * 32 + quad * 8);

  f32x4 accO[4][2];   // O^T: [d-strip n2][q-col s], lane=(d=quad*4+r, q=l15)
  float rsum[2];
#pragma unroll
  for (int n2 = 0; n2 < 4; ++n2)
#pragma unroll
    for (int s = 0; s < 2; ++s) accO[n2][s] = f32x4{0.f, 0.f, 0.f, 0.f};
  rsum[0] = rsum[1] = 0.f;

  const int sr = tid >> 3, sc = (tid & 7) * 8;
  s16x8 kreg[2], vreg[2];
#pragma unroll
  for (int hf = 0; hf < 2; ++hf) {
    kreg[hf] = *(const s16x8*)(Kh + (size_t)(kt0 * 64 + sr + hf * 32) * HD + sc);
    vreg[hf] = *(const s16x8*)(Vh + (size_t)(sr + hf * 32) * TSEQ + kt0 * 64 + sc);
  }

  for (int kt = 0; kt < ntiles; ++kt) {
    __syncthreads();
#pragma unroll
    for (int hf = 0; hf < 2; ++hf) {
      *(s16x8*)(Ksh + (sr + hf * 32) * 72 + sc) = kreg[hf];
      *(s16x8*)(Vsh + (sr + hf * 32) * 72 + sc) = vreg[hf];
    }
    __syncthreads();
    if (kt + 1 < ntiles) {
      const int k0n = (kt0 + kt + 1) * 64;
#pragma unroll
      for (int hf = 0; hf < 2; ++hf) {
        kreg[hf] = *(const s16x8*)(Kh + (size_t)(k0n + sr + hf * 32) * HD + sc);
        vreg[hf] = *(const s16x8*)(Vh + (size_t)(sr + hf * 32) * TSEQ + k0n + sc);
      }
    }

    f32x4 accS[2][4];
#pragma unroll
    for (int s = 0; s < 2; ++s)
#pragma unroll
      for (int n = 0; n < 4; ++n) accS[s][n] = f32x4{0.f, 0.f, 0.f, 0.f};
#pragma unroll
    for (int ks = 0; ks < 2; ++ks) {
#pragma unroll
      for (int n = 0; n < 4; ++n) {
        s16x8 kf = *(const s16x8*)(Ksh + (n * 16 + l15) * 72 + ks * 32 + quad * 8);
#pragma unroll
        for (int s = 0; s < 2; ++s)
          accS[s][n] = __builtin_amdgcn_mfma_f32_16x16x32_bf16(kf, qf[s][ks], accS[s][n], 0, 0, 0);
      }
    }

    // raw v_exp_f32 (R10-verified: libm exp2f's fixup was the VALU bottleneck)
    f16x4 pB[2][4];
#pragma unroll
    for (int s = 0; s < 2; ++s)
#pragma unroll
      for (int n = 0; n < 4; ++n) {
        float e0 = __builtin_amdgcn_exp2f(accS[s][n][0]);
        float e1 = __builtin_amdgcn_exp2f(accS[s][n][1]);
        float e2 = __builtin_amdgcn_exp2f(accS[s][n][2]);
        float e3 = __builtin_amdgcn_exp2f(accS[s][n][3]);
        rsum[s] += (e0 + e1) + (e2 + e3);
        f16x2 lo = __builtin_bit_cast(f16x2, __builtin_amdgcn_cvt_pkrtz(e0, e1));
        f16x2 hi = __builtin_bit_cast(f16x2, __builtin_amdgcn_cvt_pkrtz(e2, e3));
        pB[s][n] = f16x4{lo[0], lo[1], hi[0], hi[1]};
      }

#pragma unroll
    for (int n = 0; n < 4; ++n) {
#pragma unroll
      for (int n2 = 0; n2 < 4; ++n2) {
        f16x4 vA = *(const f16x4*)(Vsh + (n2 * 16 + l15) * 72 + n * 16 + quad * 4);
#pragma unroll
        for (int s = 0; s < 2; ++s)
          accO[n2][s] = __builtin_amdgcn_mfma_f32_16x16x16f16(vA, pB[s][n], accO[n2][s], 0, 0, 0);
      }
    }
  }

#pragma unroll
  for (int s = 0; s < 2; ++s) {
    float t = rsum[s];
    t += __shfl_xor(t, 16, 64);
    t += __shfl_xor(t, 32, 64);
    rsum[s] = t;
  }

  if (lsplit) {
    const int slot = (part * BATCH + b) * NH + h;
    const size_t ob = (size_t)slot * TSEQ * HD;
#pragma unroll
    for (int s = 0; s < 2; ++s) {
      const int t = q0 + s * 16 + l15;
#pragma unroll
      for (int n2 = 0; n2 < 4; ++n2) {
        const int d0 = n2 * 16 + quad * 4;
        unsigned short o[4];
#pragma unroll
        for (int r = 0; r < 4; ++r) o[r] = f2bf(accO[n2][s][r]);
        *(s16x4*)(Opart + ob + (size_t)t * HD + d0) = *(const s16x4*)o;
      }
    }
    if (quad == 0) {
      const size_t rb = (size_t)slot * TSEQ;
#pragma unroll
      for (int s = 0; s < 2; ++s)
        rsumP[rb + q0 + s * 16 + l15] = rsum[s];
    }
  } else {
#pragma unroll
    for (int s = 0; s < 2; ++s) {
      const int t = q0 + s * 16 + l15;
      const float inv = 1.f / rsum[s];
#pragma unroll
      for (int n2 = 0; n2 < 4; ++n2) {
        const int d0 = n2 * 16 + quad * 4;
        unsigned short o[4];
#pragma unroll
        for (int r = 0; r < 4; ++r) o[r] = f2bf(accO[n2][s][r] * inv);
        *(s16x4*)(ctx + ((size_t)(b * TSEQ + t)) * HID + h * HD + d0) = *(const s16x4*)o;
      }
    }
  }
}

// ---------------- combine K-split parts: ctx = sum(O_p)/sum(r_p), bf16 ----------------
__global__ __launch_bounds__(256) void combine_k(
    const unsigned short* __restrict__ Opart, const float* __restrict__ rsumP,
    unsigned short* __restrict__ ctx, int nparts) {
  const int gtid = blockIdx.x * 256 + threadIdx.x;  // 524288 total
  const int d = (gtid & 7) * 8;
  const int rem = gtid >> 3;
  const int t = rem & 2047;
  const int bh = rem >> 11;          // b*NH + h  (0..31)
  float acc[8] = {0, 0, 0, 0, 0, 0, 0, 0};
  float rs = 0.f;
  for (int p = 0; p < nparts; ++p) {
    const int slot = p * 32 + bh;
    s16x8 a = *(const s16x8*)(Opart + ((size_t)slot * TSEQ + t) * HD + d);
#pragma unroll
    for (int j = 0; j < 8; ++j) acc[j] += bf2f(((const unsigned short*)&a)[j]);
    rs += rsumP[(size_t)slot * TSEQ + t];
  }
  const float inv = 1.f / rs;
  unsigned short o[8];
#pragma unroll
  for (int j = 0; j < 8; ++j) o[j] = f2bf(acc[j] * inv);
  const int b = bh >> 4, h = bh & 15;
  *(s16x8*)(ctx + ((size_t)(b * TSEQ + t)) * HID + h * HD + d) = *(const s16x8*)o;
}

// ---------------- In-place LayerNorm over rows of 1024 ----------------
__global__ __launch_bounds__(256) void ln_k(float* __restrict__ io,
                                            const float* __restrict__ gamma,
                                            const float* __restrict__ beta) {
  const int row = blockIdx.x, tid = threadIdx.x;
  float x[4]; float s = 0.f, s2 = 0.f;
#pragma unroll
  for (int i = 0; i < 4; ++i) {
    x[i] = io[(size_t)row * HID + tid + i * 256];
    s += x[i]; s2 += x[i] * x[i];
  }
#pragma unroll
  for (int off = 1; off < 64; off <<= 1) {
    s  += __shfl_xor(s, off, 64);
    s2 += __shfl_xor(s2, off, 64);
  }
  __shared__ float red[8];
  const int wave = tid >> 6;
  if ((tid & 63) == 0) { red[wave] = s; red[wave + 4] = s2; }
  __syncthreads();
  s  = red[0] + red[1] + red[2] + red[3];
  s2 = red[4] + red[5] + red[6] + red[7];
  const float mean = s * (1.f / HID);
  const float var  = s2 * (1.f / HID) - mean * mean;
  const float rstd = rsqrtf(var + 1e-6f);
#pragma unroll
  for (int i = 0; i < 4; ++i) {
    const int col = tid + i * 256;
    io[(size_t)row * HID + col] = (x[i] - mean) * rstd * gamma[col] + beta[col];
  }
}

extern "C" void kernel_launch(void* const* d_in, const int* in_sizes, int n_in,
                              void* d_out, int out_size, void* d_ws, size_t ws_size,
                              hipStream_t stream) {
  const float* h    = (const float*)d_in[0];
  const float* Wq   = (const float*)d_in[1];
  const float* bq   = (const float*)d_in[2];
  const float* Wk   = (const float*)d_in[3];
  const float* bk   = (const float*)d_in[4];
  const float* Wv   = (const float*)d_in[5];
  const float* bv   = (const float*)d_in[6];
  const float* Wo   = (const float*)d_in[7];
  const float* bo   = (const float*)d_in[8];
  const float* gamma = (const float*)d_in[9];
  const float* beta  = (const float*)d_in[10];
  float* out = (float*)d_out;

  unsigned short* hb   = (unsigned short*)d_ws;   // bf16 h; dead after gemm_qkv -> reused as ctx
  unsigned short* wqb  = hb  + 4194304;           // 4 weights contiguous
  unsigned short* wkb  = wqb + 1048576;
  unsigned short* wvb  = wkb + 1048576;
  unsigned short* wob  = wvb + 1048576;
  unsigned short* qb   = wob + 1048576;           // bf16 [B,NH,T,D]
  unsigned short* kb   = qb  + 4194304;
  unsigned short* vtf  = kb  + 4194304;           // f16 [B,NH,D,T], written by gemm_qkv directly
  unsigned short* Opart = vtf + 4194304;          // bf16 partials (2 parts x 8 MiB)
  unsigned short* ctxb = hb;                      // ctx aliases dead hb

  const size_t base = (size_t)(vtf + 4194304 - hb) * 2;  // bytes before Opart (40 MiB)
  int lsplit = 0;
  if (ws_size >= base + 2u * 8388608 + 2u * 262144) lsplit = 1;  // ~57 MiB
  const int nparts = 1 << lsplit;
  float* rsumP = (float*)(Opart + (size_t)nparts * 4194304);

  cast_all_k<<<8192, 256, 0, stream>>>(h, Wq, Wk, Wv, Wo, hb, wqb);
  gemm_qkv<<<dim3(16, 32, 3), 256, 0, stream>>>(hb, wqb, wkb, wvb, bq, bk, bv, qb, kb, vtf);
  attn_k<<<dim3(TSEQ / 128, NH, BATCH << lsplit), 256, 0, stream>>>(
      qb, kb, vtf, ctxb, Opart, rsumP, lsplit, 32 >> lsplit);
  if (lsplit)
    combine_k<<<2048, 256, 0, stream>>>(Opart, rsumP, ctxb, nparts);
  gemm_out<<<dim3(16, 32), 256, 0, stream>>>(ctxb, wob, bo, h, out);
  ln_k<<<4096, 256, 0, stream>>>(out, gamma, beta);
}

// Round 12
// 220.769 us; speedup vs baseline: 1.1067x; 1.0241x over previous
//
#include <hip/hip_runtime.h>
#include <hip/hip_bf16.h>

#define NH   16
#define HD   64
#define HID  1024
#define TSEQ 2048
#define BATCH 2
#define KSCALE 0.18033688011112042f   // 0.125 * log2(e), folded into Wk/bk

typedef __attribute__((ext_vector_type(4))) float f32x4;
typedef __attribute__((ext_vector_type(8))) short s16x8;
typedef __attribute__((ext_vector_type(4))) short s16x4;
typedef __attribute__((ext_vector_type(8))) _Float16 f16x8;
typedef __attribute__((ext_vector_type(4))) _Float16 f16x4;
typedef __attribute__((ext_vector_type(2))) _Float16 f16x2;

__device__ __forceinline__ unsigned short f2bf(float f) {
  union { float f; unsigned int u; } v; v.f = f;
  unsigned int r = v.u + 0x7fffu + ((v.u >> 16) & 1u);
  return (unsigned short)(r >> 16);
}
__device__ __forceinline__ float bf2f(unsigned short b) {
  union { unsigned int u; float f; } v; v.u = ((unsigned int)b) << 16; return v.f;
}

__device__ __forceinline__ void async_cp16(const unsigned short* g, unsigned short* l) {
  __builtin_amdgcn_global_load_lds(
      (const __attribute__((address_space(1))) unsigned int*)g,
      (__attribute__((address_space(3))) unsigned int*)l, 16, 0, 0);
}

// ---------------- one cast kernel: h + all 4 weights (Wk pre-scaled) ----------------
__global__ __launch_bounds__(256) void cast_all_k(
    const float* __restrict__ h,
    const float* __restrict__ w0, const float* __restrict__ w1,
    const float* __restrict__ w2, const float* __restrict__ w3,
    unsigned short* __restrict__ hb, unsigned short* __restrict__ wbase) {
  int i = blockIdx.x * 256 + threadIdx.x;  // 2097152 float4 total
  const float* src; unsigned short* dst; int idx; float sc = 1.f;
  if (i < 1048576) { src = h; dst = hb; idx = i; }
  else {
    int idx4 = i - 1048576;
    int w = idx4 >> 18;
    idx = idx4 & 262143;
    src = (w == 0) ? w0 : (w == 1) ? w1 : (w == 2) ? w2 : w3;
    dst = wbase + (size_t)(idx4 - idx) * 4;   // contiguous weight region
    if (w == 1) sc = KSCALE;
  }
  float4 v = ((const float4*)src)[idx];
  ushort4 o;
  o.x = f2bf(v.x * sc); o.y = f2bf(v.y * sc); o.z = f2bf(v.z * sc); o.w = f2bf(v.w * sc);
  ((ushort4*)dst)[idx] = o;
}

// ---------------- Fused QKV projection, 64x64 tile, 3 matrices per block ----------------
// One A-stage feeds Q,K,V B-tiles: 24 MFMA per barrier-pair (vs 8 unfused).
// Wave w owns cols [w*16, w*16+16) of the 64-col tile for ALL 3 matrices.
__global__ __launch_bounds__(256) void gemm_qkv(
    const unsigned short* __restrict__ hb,
    const unsigned short* __restrict__ wq, const unsigned short* __restrict__ wk,
    const unsigned short* __restrict__ wv,
    const float* __restrict__ bq, const float* __restrict__ bk, const float* __restrict__ bv,
    unsigned short* __restrict__ qo, unsigned short* __restrict__ ko,
    unsigned short* __restrict__ vto) {
  __shared__ unsigned short Ash[64 * 32];       // 4 KB
  __shared__ unsigned short Bsh[3][64 * 32];    // 12 KB
  const int tid = threadIdx.x, lane = tid & 63, wave = tid >> 6;
  const int l15 = lane & 15, quad = lane >> 4;
  const int wn = wave * 16;
  const int bm = blockIdx.y * 64, bn = blockIdx.x * 64;
  const unsigned short* Ag = hb + (size_t)bm * HID;
  const unsigned short* Bg0 = wq + (size_t)bn * HID;
  const unsigned short* Bg1 = wk + (size_t)bn * HID;
  const unsigned short* Bg2 = wv + (size_t)bn * HID;
  const int idx = tid * 8;            // 0..2047: one cp16/thread per 64x32 tile
  const int rA = idx >> 5, cA = idx & 31;

  f32x4 acc[3][4];                    // [matrix][M-strip]
#pragma unroll
  for (int m = 0; m < 3; ++m)
#pragma unroll
    for (int i = 0; i < 4; ++i) acc[m][i] = f32x4{0.f, 0.f, 0.f, 0.f};

  for (int k0 = 0; k0 < HID; k0 += 32) {
    __syncthreads();
    async_cp16(Ag  + rA * HID + k0 + cA, Ash    + idx);
    async_cp16(Bg0 + rA * HID + k0 + cA, Bsh[0] + idx);
    async_cp16(Bg1 + rA * HID + k0 + cA, Bsh[1] + idx);
    async_cp16(Bg2 + rA * HID + k0 + cA, Bsh[2] + idx);
    __syncthreads();
    s16x8 af[4];
#pragma unroll
    for (int i = 0; i < 4; ++i)
      af[i] = *(const s16x8*)(Ash + (i * 16 + l15) * 32 + quad * 8);
#pragma unroll
    for (int m = 0; m < 3; ++m) {
      s16x8 bfr = *(const s16x8*)(Bsh[m] + (wn + l15) * 32 + quad * 8);
#pragma unroll
      for (int i = 0; i < 4; ++i)
        acc[m][i] = __builtin_amdgcn_mfma_f32_16x16x32_bf16(af[i], bfr, acc[m][i], 0, 0, 0);
    }
  }

  const int col = bn + wn + l15;
  const int head = col >> 6, d = col & 63;
  // Q
  {
    const float bb = bq[col];
#pragma unroll
    for (int i = 0; i < 4; ++i) {
#pragma unroll
      for (int r = 0; r < 4; ++r) {
        const int row = bm + i * 16 + quad * 4 + r;
        const int bI = row >> 11, t = row & 2047;
        qo[(((size_t)(bI * NH + head) * TSEQ) + t) * HD + d] = f2bf(acc[0][i][r] + bb);
      }
    }
  }
  // K (pre-scaled domain)
  {
    const float bb = bk[col] * KSCALE;
#pragma unroll
    for (int i = 0; i < 4; ++i) {
#pragma unroll
      for (int r = 0; r < 4; ++r) {
        const int row = bm + i * 16 + quad * 4 + r;
        const int bI = row >> 11, t = row & 2047;
        ko[(((size_t)(bI * NH + head) * TSEQ) + t) * HD + d] = f2bf(acc[1][i][r] + bb);
      }
    }
  }
  // V: f16, transposed [B,NH,D,T]; 4 consecutive t per lane = 8B store
  {
    const float bb = bv[col];
#pragma unroll
    for (int i = 0; i < 4; ++i) {
      const int row0 = bm + i * 16 + quad * 4;
      const int bI = row0 >> 11, t0 = row0 & 2047;
      unsigned short o[4];
#pragma unroll
      for (int r = 0; r < 4; ++r) {
        _Float16 hv = (_Float16)(acc[2][i][r] + bb);
        o[r] = __builtin_bit_cast(unsigned short, hv);
      }
      *(s16x4*)(vto + ((size_t)((bI * NH + head) * HD + d)) * TSEQ + t0) = *(const s16x4*)o;
    }
  }
}

// ---------------- Output projection, 128x64 tiles: out = ctx @ Wo^T + bo + h ----------------
__global__ __launch_bounds__(256) void gemm_out(
    const unsigned short* __restrict__ ctx, const unsigned short* __restrict__ wo,
    const float* __restrict__ bo, const float* __restrict__ hres,
    float* __restrict__ outf) {
  __shared__ unsigned short Ash[128 * 32];
  __shared__ unsigned short Bsh[64 * 32];
  const int tid = threadIdx.x, lane = tid & 63, wave = tid >> 6;
  const int l15 = lane & 15, quad = lane >> 4;
  const int wm = (wave >> 1) * 64, wn = (wave & 1) * 32;
  const int bm = blockIdx.y * 128, bn = blockIdx.x * 64;
  const unsigned short* Ag = ctx + (size_t)bm * HID;
  const unsigned short* Bg = wo + (size_t)bn * HID;
  const int idx0 = tid * 8, idx1 = idx0 + 2048;
  const int r0 = idx0 >> 5, c0 = idx0 & 31;
  const int r1 = idx1 >> 5, c1 = idx1 & 31;
  f32x4 acc[4][2];
#pragma unroll
  for (int i = 0; i < 4; ++i)
#pragma unroll
    for (int j = 0; j < 2; ++j) acc[i][j] = f32x4{0.f, 0.f, 0.f, 0.f};

  for (int k0 = 0; k0 < HID; k0 += 32) {
    __syncthreads();
    async_cp16(Ag + r0 * HID + k0 + c0, Ash + idx0);
    async_cp16(Ag + r1 * HID + k0 + c1, Ash + idx1);
    async_cp16(Bg + r0 * HID + k0 + c0, Bsh + idx0);
    __syncthreads();
    s16x8 af[4], bfr[2];
#pragma unroll
    for (int i = 0; i < 4; ++i)
      af[i] = *(const s16x8*)(Ash + (wm + i * 16 + l15) * 32 + quad * 8);
#pragma unroll
    for (int j = 0; j < 2; ++j)
      bfr[j] = *(const s16x8*)(Bsh + (wn + j * 16 + l15) * 32 + quad * 8);
#pragma unroll
    for (int i = 0; i < 4; ++i)
#pragma unroll
      for (int j = 0; j < 2; ++j)
        acc[i][j] = __builtin_amdgcn_mfma_f32_16x16x32_bf16(af[i], bfr[j], acc[i][j], 0, 0, 0);
  }
#pragma unroll
  for (int j = 0; j < 2; ++j) {
    const int col = bn + wn + j * 16 + l15;
    const float bb = bo[col];
#pragma unroll
    for (int i = 0; i < 4; ++i) {
#pragma unroll
      for (int r = 0; r < 4; ++r) {
        const int row = bm + wm + i * 16 + quad * 4 + r;
        const size_t off = (size_t)row * HID + col;
        outf[off] = acc[i][j][r] + bb + hres[off];
      }
    }
  }
}

// ---------------- Flash attention: S^T formulation, K-split by 1/2 ----------------
__global__ __launch_bounds__(256, 2) void attn_k(
    const unsigned short* __restrict__ qb, const unsigned short* __restrict__ kb,
    const unsigned short* __restrict__ vt, unsigned short* __restrict__ ctx,
    unsigned short* __restrict__ Opart, float* __restrict__ rsumP,
    int lsplit, int ntiles) {
  __shared__ unsigned short Ksh[64 * 72];   // bf16 [key][d]
  __shared__ unsigned short Vsh[64 * 72];   // f16  [d][key]

  const int tid = threadIdx.x, lane = tid & 63, wave = tid >> 6;
  const int l15 = lane & 15, quad = lane >> 4;
  const int z = blockIdx.z;
  const int b = z >> lsplit;
  const int part = z & ((1 << lsplit) - 1);
  const int h = blockIdx.y, qt = blockIdx.x;
  const size_t ho = ((size_t)(b * NH + h)) * TSEQ * HD;
  const unsigned short* Qh = qb + ho;
  const unsigned short* Kh = kb + ho;
  const unsigned short* Vh = vt + ho;
  const int q0 = qt * 128 + wave * 32;
  const int kt0 = part * ntiles;

  s16x8 qf[2][2];
#pragma unroll
  for (int s = 0; s < 2; ++s)
#pragma unroll
    for (int ks = 0; ks < 2; ++ks)
      qf[s][ks] = *(const s16x8*)(Qh + (size_t)(q0 + s * 16 + l15) * HD + ks * 32 + quad * 8);

  f32x4 accO[4][2];   // O^T: [d-strip n2][q-col s], lane=(d=quad*4+r, q=l15)
  float rsum[2];
#pragma unroll
  for (int n2 = 0; n2 < 4; ++n2)
#pragma unroll
    for (int s = 0; s < 2; ++s) accO[n2][s] = f32x4{0.f, 0.f, 0.f, 0.f};
  rsum[0] = rsum[1] = 0.f;

  const int sr = tid >> 3, sc = (tid & 7) * 8;
  s16x8 kreg[2], vreg[2];
#pragma unroll
  for (int hf = 0; hf < 2; ++hf) {
    kreg[hf] = *(const s16x8*)(Kh + (size_t)(kt0 * 64 + sr + hf * 32) * HD + sc);
    vreg[hf] = *(const s16x8*)(Vh + (size_t)(sr + hf * 32) * TSEQ + kt0 * 64 + sc);
  }

  for (int kt = 0; kt < ntiles; ++kt) {
    __syncthreads();
#pragma unroll
    for (int hf = 0; hf < 2; ++hf) {
      *(s16x8*)(Ksh + (sr + hf * 32) * 72 + sc) = kreg[hf];
      *(s16x8*)(Vsh + (sr + hf * 32) * 72 + sc) = vreg[hf];
    }
    __syncthreads();
    if (kt + 1 < ntiles) {
      const int k0n = (kt0 + kt + 1) * 64;
#pragma unroll
      for (int hf = 0; hf < 2; ++hf) {
        kreg[hf] = *(const s16x8*)(Kh + (size_t)(k0n + sr + hf * 32) * HD + sc);
        vreg[hf] = *(const s16x8*)(Vh + (size_t)(sr + hf * 32) * TSEQ + k0n + sc);
      }
    }

    f32x4 accS[2][4];
#pragma unroll
    for (int s = 0; s < 2; ++s)
#pragma unroll
      for (int n = 0; n < 4; ++n) accS[s][n] = f32x4{0.f, 0.f, 0.f, 0.f};
#pragma unroll
    for (int ks = 0; ks < 2; ++ks) {
#pragma unroll
      for (int n = 0; n < 4; ++n) {
        s16x8 kf = *(const s16x8*)(Ksh + (n * 16 + l15) * 72 + ks * 32 + quad * 8);
#pragma unroll
        for (int s = 0; s < 2; ++s)
          accS[s][n] = __builtin_amdgcn_mfma_f32_16x16x32_bf16(kf, qf[s][ks], accS[s][n], 0, 0, 0);
      }
    }

    // raw v_exp_f32 (R10-verified: libm exp2f's fixup was the VALU bottleneck)
    f16x4 pB[2][4];
#pragma unroll
    for (int s = 0; s < 2; ++s)
#pragma unroll
      for (int n = 0; n < 4; ++n) {
        float e0 = __builtin_amdgcn_exp2f(accS[s][n][0]);
        float e1 = __builtin_amdgcn_exp2f(accS[s][n][1]);
        float e2 = __builtin_amdgcn_exp2f(accS[s][n][2]);
        float e3 = __builtin_amdgcn_exp2f(accS[s][n][3]);
        rsum[s] += (e0 + e1) + (e2 + e3);
        f16x2 lo = __builtin_bit_cast(f16x2, __builtin_amdgcn_cvt_pkrtz(e0, e1));
        f16x2 hi = __builtin_bit_cast(f16x2, __builtin_amdgcn_cvt_pkrtz(e2, e3));
        pB[s][n] = f16x4{lo[0], lo[1], hi[0], hi[1]};
      }

#pragma unroll
    for (int n = 0; n < 4; ++n) {
#pragma unroll
      for (int n2 = 0; n2 < 4; ++n2) {
        f16x4 vA = *(const f16x4*)(Vsh + (n2 * 16 + l15) * 72 + n * 16 + quad * 4);
#pragma unroll
        for (int s = 0; s < 2; ++s)
          accO[n2][s] = __builtin_amdgcn_mfma_f32_16x16x16f16(vA, pB[s][n], accO[n2][s], 0, 0, 0);
      }
    }
  }

#pragma unroll
  for (int s = 0; s < 2; ++s) {
    float t = rsum[s];
    t += __shfl_xor(t, 16, 64);
    t += __shfl_xor(t, 32, 64);
    rsum[s] = t;
  }

  if (lsplit) {
    const int slot = (part * BATCH + b) * NH + h;
    const size_t ob = (size_t)slot * TSEQ * HD;
#pragma unroll
    for (int s = 0; s < 2; ++s) {
      const int t = q0 + s * 16 + l15;
#pragma unroll
      for (int n2 = 0; n2 < 4; ++n2) {
        const int d0 = n2 * 16 + quad * 4;
        unsigned short o[4];
#pragma unroll
        for (int r = 0; r < 4; ++r) o[r] = f2bf(accO[n2][s][r]);
        *(s16x4*)(Opart + ob + (size_t)t * HD + d0) = *(const s16x4*)o;
      }
    }
    if (quad == 0) {
      const size_t rb = (size_t)slot * TSEQ;
#pragma unroll
      for (int s = 0; s < 2; ++s)
        rsumP[rb + q0 + s * 16 + l15] = rsum[s];
    }
  } else {
#pragma unroll
    for (int s = 0; s < 2; ++s) {
      const int t = q0 + s * 16 + l15;
      const float inv = 1.f / rsum[s];
#pragma unroll
      for (int n2 = 0; n2 < 4; ++n2) {
        const int d0 = n2 * 16 + quad * 4;
        unsigned short o[4];
#pragma unroll
        for (int r = 0; r < 4; ++r) o[r] = f2bf(accO[n2][s][r] * inv);
        *(s16x4*)(ctx + ((size_t)(b * TSEQ + t)) * HID + h * HD + d0) = *(const s16x4*)o;
      }
    }
  }
}

// ---------------- combine K-split parts: ctx = sum(O_p)/sum(r_p), bf16 ----------------
__global__ __launch_bounds__(256) void combine_k(
    const unsigned short* __restrict__ Opart, const float* __restrict__ rsumP,
    unsigned short* __restrict__ ctx, int nparts) {
  const int gtid = blockIdx.x * 256 + threadIdx.x;  // 524288 total
  const int d = (gtid & 7) * 8;
  const int rem = gtid >> 3;
  const int t = rem & 2047;
  const int bh = rem >> 11;          // b*NH + h  (0..31)
  float acc[8] = {0, 0, 0, 0, 0, 0, 0, 0};
  float rs = 0.f;
  for (int p = 0; p < nparts; ++p) {
    const int slot = p * 32 + bh;
    s16x8 a = *(const s16x8*)(Opart + ((size_t)slot * TSEQ + t) * HD + d);
#pragma unroll
    for (int j = 0; j < 8; ++j) acc[j] += bf2f(((const unsigned short*)&a)[j]);
    rs += rsumP[(size_t)slot * TSEQ + t];
  }
  const float inv = 1.f / rs;
  unsigned short o[8];
#pragma unroll
  for (int j = 0; j < 8; ++j) o[j] = f2bf(acc[j] * inv);
  const int b = bh >> 4, h = bh & 15;
  *(s16x8*)(ctx + ((size_t)(b * TSEQ + t)) * HID + h * HD + d) = *(const s16x8*)o;
}

// ---------------- In-place LayerNorm over rows of 1024 ----------------
__global__ __launch_bounds__(256) void ln_k(float* __restrict__ io,
                                            const float* __restrict__ gamma,
                                            const float* __restrict__ beta) {
  const int row = blockIdx.x, tid = threadIdx.x;
  float x[4]; float s = 0.f, s2 = 0.f;
#pragma unroll
  for (int i = 0; i < 4; ++i) {
    x[i] = io[(size_t)row * HID + tid + i * 256];
    s += x[i]; s2 += x[i] * x[i];
  }
#pragma unroll
  for (int off = 1; off < 64; off <<= 1) {
    s  += __shfl_xor(s, off, 64);
    s2 += __shfl_xor(s2, off, 64);
  }
  __shared__ float red[8];
  const int wave = tid >> 6;
  if ((tid & 63) == 0) { red[wave] = s; red[wave + 4] = s2; }
  __syncthreads();
  s  = red[0] + red[1] + red[2] + red[3];
  s2 = red[4] + red[5] + red[6] + red[7];
  const float mean = s * (1.f / HID);
  const float var  = s2 * (1.f / HID) - mean * mean;
  const float rstd = rsqrtf(var + 1e-6f);
#pragma unroll
  for (int i = 0; i < 4; ++i) {
    const int col = tid + i * 256;
    io[(size_t)row * HID + col] = (x[i] - mean) * rstd * gamma[col] + beta[col];
  }
}

extern "C" void kernel_launch(void* const* d_in, const int* in_sizes, int n_in,
                              void* d_out, int out_size, void* d_ws, size_t ws_size,
                              hipStream_t stream) {
  const float* h    = (const float*)d_in[0];
  const float* Wq   = (const float*)d_in[1];
  const float* bq   = (const float*)d_in[2];
  const float* Wk   = (const float*)d_in[3];
  const float* bk   = (const float*)d_in[4];
  const float* Wv   = (const float*)d_in[5];
  const float* bv   = (const float*)d_in[6];
  const float* Wo   = (const float*)d_in[7];
  const float* bo   = (const float*)d_in[8];
  const float* gamma = (const float*)d_in[9];
  const float* beta  = (const float*)d_in[10];
  float* out = (float*)d_out;

  unsigned short* hb   = (unsigned short*)d_ws;   // bf16 h; dead after gemm_qkv -> reused as ctx
  unsigned short* wqb  = hb  + 4194304;           // 4 weights contiguous
  unsigned short* wkb  = wqb + 1048576;
  unsigned short* wvb  = wkb + 1048576;
  unsigned short* wob  = wvb + 1048576;
  unsigned short* qb   = wob + 1048576;           // bf16 [B,NH,T,D]
  unsigned short* kb   = qb  + 4194304;
  unsigned short* vtf  = kb  + 4194304;           // f16 [B,NH,D,T], written by gemm_qkv directly
  unsigned short* Opart = vtf + 4194304;          // bf16 partials (2 parts x 8 MiB)
  unsigned short* ctxb = hb;                      // ctx aliases dead hb

  const size_t base = (size_t)(vtf + 4194304 - hb) * 2;  // bytes before Opart (40 MiB)
  int lsplit = 0;
  if (ws_size >= base + 2u * 8388608 + 2u * 262144) lsplit = 1;  // ~57 MiB
  const int nparts = 1 << lsplit;
  float* rsumP = (float*)(Opart + (size_t)nparts * 4194304);

  cast_all_k<<<8192, 256, 0, stream>>>(h, Wq, Wk, Wv, Wo, hb, wqb);
  gemm_qkv<<<dim3(16, 64), 256, 0, stream>>>(hb, wqb, wkb, wvb, bq, bk, bv, qb, kb, vtf);
  attn_k<<<dim3(TSEQ / 128, NH, BATCH << lsplit), 256, 0, stream>>>(
      qb, kb, vtf, ctxb, Opart, rsumP, lsplit, 32 >> lsplit);
  if (lsplit)
    combine_k<<<2048, 256, 0, stream>>>(Opart, rsumP, ctxb, nparts);
  gemm_out<<<dim3(16, 32), 256, 0, stream>>>(ctxb, wob, bo, h, out);
  ln_k<<<4096, 256, 0, stream>>>(out, gamma, beta);
}

// Round 13
// 219.501 us; speedup vs baseline: 1.1131x; 1.0058x over previous
//
#include <hip/hip_runtime.h>
#include <hip/hip_bf16.h>

#define NH   16
#define HD   64
#define HID  1024
#define TSEQ 2048
#define BATCH 2
#define KSCALE 0.18033688011112042f   // 0.125 * log2(e), folded into Wk/bk

typedef __attribute__((ext_vector_type(4))) float f32x4;
typedef __attribute__((ext_vector_type(8))) short s16x8;
typedef __attribute__((ext_vector_type(4))) short s16x4;
typedef __attribute__((ext_vector_type(8))) _Float16 f16x8;
typedef __attribute__((ext_vector_type(4))) _Float16 f16x4;
typedef __attribute__((ext_vector_type(2))) _Float16 f16x2;

__device__ __forceinline__ unsigned short f2bf(float f) {
  union { float f; unsigned int u; } v; v.f = f;
  unsigned int r = v.u + 0x7fffu + ((v.u >> 16) & 1u);
  return (unsigned short)(r >> 16);
}
__device__ __forceinline__ float bf2f(unsigned short b) {
  union { unsigned int u; float f; } v; v.u = ((unsigned int)b) << 16; return v.f;
}

// ---------------- one cast kernel: h + all 4 weights (Wk pre-scaled) ----------------
__global__ __launch_bounds__(256) void cast_all_k(
    const float* __restrict__ h,
    const float* __restrict__ w0, const float* __restrict__ w1,
    const float* __restrict__ w2, const float* __restrict__ w3,
    unsigned short* __restrict__ hb, unsigned short* __restrict__ wbase) {
  int i = blockIdx.x * 256 + threadIdx.x;  // 2097152 float4 total
  const float* src; unsigned short* dst; int idx; float sc = 1.f;
  if (i < 1048576) { src = h; dst = hb; idx = i; }
  else {
    int idx4 = i - 1048576;
    int w = idx4 >> 18;
    idx = idx4 & 262143;
    src = (w == 0) ? w0 : (w == 1) ? w1 : (w == 2) ? w2 : w3;
    dst = wbase + (size_t)(idx4 - idx) * 4;   // contiguous weight region
    if (w == 1) sc = KSCALE;
  }
  float4 v = ((const float4*)src)[idx];
  ushort4 o;
  o.x = f2bf(v.x * sc); o.y = f2bf(v.y * sc); o.z = f2bf(v.z * sc); o.w = f2bf(v.w * sc);
  ((ushort4*)dst)[idx] = o;
}

// ---------------- Fused QKV projection, 64x64 tile, register-prefetch staging ----------------
// attn_k-style: next K-step's chunks load into VGPRs during compute, ds_write
// after barrier — global latency overlaps compute instead of draining at vmcnt(0).
__global__ __launch_bounds__(256) void gemm_qkv(
    const unsigned short* __restrict__ hb,
    const unsigned short* __restrict__ wq, const unsigned short* __restrict__ wk,
    const unsigned short* __restrict__ wv,
    const float* __restrict__ bq, const float* __restrict__ bk, const float* __restrict__ bv,
    unsigned short* __restrict__ qo, unsigned short* __restrict__ ko,
    unsigned short* __restrict__ vto) {
  __shared__ unsigned short Ash[64 * 32];       // 4 KB
  __shared__ unsigned short Bsh[3][64 * 32];    // 12 KB
  const int tid = threadIdx.x, lane = tid & 63, wave = tid >> 6;
  const int l15 = lane & 15, quad = lane >> 4;
  const int wn = wave * 16;
  const int bm = blockIdx.y * 64, bn = blockIdx.x * 64;
  const unsigned short* Ag = hb + (size_t)bm * HID;
  const unsigned short* Bg0 = wq + (size_t)bn * HID;
  const unsigned short* Bg1 = wk + (size_t)bn * HID;
  const unsigned short* Bg2 = wv + (size_t)bn * HID;
  const int idx = tid * 8;            // one 8-elem chunk/thread per 64x32 tile
  const int rA = idx >> 5, cA = idx & 31;
  const size_t goff = (size_t)rA * HID + cA;

  f32x4 acc[3][4];
#pragma unroll
  for (int m = 0; m < 3; ++m)
#pragma unroll
    for (int i = 0; i < 4; ++i) acc[m][i] = f32x4{0.f, 0.f, 0.f, 0.f};

  s16x8 pa, pb0, pb1, pb2;
  pa  = *(const s16x8*)(Ag  + goff);
  pb0 = *(const s16x8*)(Bg0 + goff);
  pb1 = *(const s16x8*)(Bg1 + goff);
  pb2 = *(const s16x8*)(Bg2 + goff);

  for (int k0 = 0; k0 < HID; k0 += 32) {
    __syncthreads();
    *(s16x8*)(Ash    + idx) = pa;
    *(s16x8*)(Bsh[0] + idx) = pb0;
    *(s16x8*)(Bsh[1] + idx) = pb1;
    *(s16x8*)(Bsh[2] + idx) = pb2;
    __syncthreads();
    if (k0 + 32 < HID) {
      pa  = *(const s16x8*)(Ag  + goff + k0 + 32);
      pb0 = *(const s16x8*)(Bg0 + goff + k0 + 32);
      pb1 = *(const s16x8*)(Bg1 + goff + k0 + 32);
      pb2 = *(const s16x8*)(Bg2 + goff + k0 + 32);
    }
    s16x8 af[4];
#pragma unroll
    for (int i = 0; i < 4; ++i)
      af[i] = *(const s16x8*)(Ash + (i * 16 + l15) * 32 + quad * 8);
#pragma unroll
    for (int m = 0; m < 3; ++m) {
      s16x8 bfr = *(const s16x8*)(Bsh[m] + (wn + l15) * 32 + quad * 8);
#pragma unroll
      for (int i = 0; i < 4; ++i)
        acc[m][i] = __builtin_amdgcn_mfma_f32_16x16x32_bf16(af[i], bfr, acc[m][i], 0, 0, 0);
    }
  }

  const int col = bn + wn + l15;
  const int head = col >> 6, d = col & 63;
  // Q
  {
    const float bb = bq[col];
#pragma unroll
    for (int i = 0; i < 4; ++i) {
#pragma unroll
      for (int r = 0; r < 4; ++r) {
        const int row = bm + i * 16 + quad * 4 + r;
        const int bI = row >> 11, t = row & 2047;
        qo[(((size_t)(bI * NH + head) * TSEQ) + t) * HD + d] = f2bf(acc[0][i][r] + bb);
      }
    }
  }
  // K (pre-scaled domain)
  {
    const float bb = bk[col] * KSCALE;
#pragma unroll
    for (int i = 0; i < 4; ++i) {
#pragma unroll
      for (int r = 0; r < 4; ++r) {
        const int row = bm + i * 16 + quad * 4 + r;
        const int bI = row >> 11, t = row & 2047;
        ko[(((size_t)(bI * NH + head) * TSEQ) + t) * HD + d] = f2bf(acc[1][i][r] + bb);
      }
    }
  }
  // V: f16, transposed [B,NH,D,T]; 4 consecutive t per lane = 8B store
  {
    const float bb = bv[col];
#pragma unroll
    for (int i = 0; i < 4; ++i) {
      const int row0 = bm + i * 16 + quad * 4;
      const int bI = row0 >> 11, t0 = row0 & 2047;
      unsigned short o[4];
#pragma unroll
      for (int r = 0; r < 4; ++r) {
        _Float16 hv = (_Float16)(acc[2][i][r] + bb);
        o[r] = __builtin_bit_cast(unsigned short, hv);
      }
      *(s16x4*)(vto + ((size_t)((bI * NH + head) * HD + d)) * TSEQ + t0) = *(const s16x4*)o;
    }
  }
}

// ---------------- Output projection, 128x64 tiles, register-prefetch staging ----------------
__global__ __launch_bounds__(256) void gemm_out(
    const unsigned short* __restrict__ ctx, const unsigned short* __restrict__ wo,
    const float* __restrict__ bo, const float* __restrict__ hres,
    float* __restrict__ outf) {
  __shared__ unsigned short Ash[128 * 32];
  __shared__ unsigned short Bsh[64 * 32];
  const int tid = threadIdx.x, lane = tid & 63, wave = tid >> 6;
  const int l15 = lane & 15, quad = lane >> 4;
  const int wm = (wave >> 1) * 64, wn = (wave & 1) * 32;
  const int bm = blockIdx.y * 128, bn = blockIdx.x * 64;
  const unsigned short* Ag = ctx + (size_t)bm * HID;
  const unsigned short* Bg = wo + (size_t)bn * HID;
  const int idx0 = tid * 8, idx1 = idx0 + 2048;
  const int r0 = idx0 >> 5, c0 = idx0 & 31;
  const int r1 = idx1 >> 5, c1 = idx1 & 31;
  const size_t g0 = (size_t)r0 * HID + c0, g1 = (size_t)r1 * HID + c1;
  f32x4 acc[4][2];
#pragma unroll
  for (int i = 0; i < 4; ++i)
#pragma unroll
    for (int j = 0; j < 2; ++j) acc[i][j] = f32x4{0.f, 0.f, 0.f, 0.f};

  s16x8 pa0 = *(const s16x8*)(Ag + g0);
  s16x8 pa1 = *(const s16x8*)(Ag + g1);
  s16x8 pb  = *(const s16x8*)(Bg + g0);

  for (int k0 = 0; k0 < HID; k0 += 32) {
    __syncthreads();
    *(s16x8*)(Ash + idx0) = pa0;
    *(s16x8*)(Ash + idx1) = pa1;
    *(s16x8*)(Bsh + idx0) = pb;
    __syncthreads();
    if (k0 + 32 < HID) {
      pa0 = *(const s16x8*)(Ag + g0 + k0 + 32);
      pa1 = *(const s16x8*)(Ag + g1 + k0 + 32);
      pb  = *(const s16x8*)(Bg + g0 + k0 + 32);
    }
    s16x8 af[4], bfr[2];
#pragma unroll
    for (int i = 0; i < 4; ++i)
      af[i] = *(const s16x8*)(Ash + (wm + i * 16 + l15) * 32 + quad * 8);
#pragma unroll
    for (int j = 0; j < 2; ++j)
      bfr[j] = *(const s16x8*)(Bsh + (wn + j * 16 + l15) * 32 + quad * 8);
#pragma unroll
    for (int i = 0; i < 4; ++i)
#pragma unroll
      for (int j = 0; j < 2; ++j)
        acc[i][j] = __builtin_amdgcn_mfma_f32_16x16x32_bf16(af[i], bfr[j], acc[i][j], 0, 0, 0);
  }
#pragma unroll
  for (int j = 0; j < 2; ++j) {
    const int col = bn + wn + j * 16 + l15;
    const float bb = bo[col];
#pragma unroll
    for (int i = 0; i < 4; ++i) {
#pragma unroll
      for (int r = 0; r < 4; ++r) {
        const int row = bm + wm + i * 16 + quad * 4 + r;
        const size_t off = (size_t)row * HID + col;
        outf[off] = acc[i][j][r] + bb + hres[off];
      }
    }
  }
}

// ---------------- Flash attention: S^T formulation, K-split by 1/2 ----------------
__global__ __launch_bounds__(256, 2) void attn_k(
    const unsigned short* __restrict__ qb, const unsigned short* __restrict__ kb,
    const unsigned short* __restrict__ vt, unsigned short* __restrict__ ctx,
    unsigned short* __restrict__ Opart, float* __restrict__ rsumP,
    int lsplit, int ntiles) {
  __shared__ unsigned short Ksh[64 * 72];   // bf16 [key][d]
  __shared__ unsigned short Vsh[64 * 72];   // f16  [d][key]

  const int tid = threadIdx.x, lane = tid & 63, wave = tid >> 6;
  const int l15 = lane & 15, quad = lane >> 4;
  const int z = blockIdx.z;
  const int b = z >> lsplit;
  const int part = z & ((1 << lsplit) - 1);
  const int h = blockIdx.y, qt = blockIdx.x;
  const size_t ho = ((size_t)(b * NH + h)) * TSEQ * HD;
  const unsigned short* Qh = qb + ho;
  const unsigned short* Kh = kb + ho;
  const unsigned short* Vh = vt + ho;
  const int q0 = qt * 128 + wave * 32;
  const int kt0 = part * ntiles;

  s16x8 qf[2][2];
#pragma unroll
  for (int s = 0; s < 2; ++s)
#pragma unroll
    for (int ks = 0; ks < 2; ++ks)
      qf[s][ks] = *(const s16x8*)(Qh + (size_t)(q0 + s * 16 + l15) * HD + ks * 32 + quad * 8);

  f32x4 accO[4][2];   // O^T: [d-strip n2][q-col s], lane=(d=quad*4+r, q=l15)
  float rsum[2];
#pragma unroll
  for (int n2 = 0; n2 < 4; ++n2)
#pragma unroll
    for (int s = 0; s < 2; ++s) accO[n2][s] = f32x4{0.f, 0.f, 0.f, 0.f};
  rsum[0] = rsum[1] = 0.f;

  const int sr = tid >> 3, sc = (tid & 7) * 8;
  s16x8 kreg[2], vreg[2];
#pragma unroll
  for (int hf = 0; hf < 2; ++hf) {
    kreg[hf] = *(const s16x8*)(Kh + (size_t)(kt0 * 64 + sr + hf * 32) * HD + sc);
    vreg[hf] = *(const s16x8*)(Vh + (size_t)(sr + hf * 32) * TSEQ + kt0 * 64 + sc);
  }

  for (int kt = 0; kt < ntiles; ++kt) {
    __syncthreads();
#pragma unroll
    for (int hf = 0; hf < 2; ++hf) {
      *(s16x8*)(Ksh + (sr + hf * 32) * 72 + sc) = kreg[hf];
      *(s16x8*)(Vsh + (sr + hf * 32) * 72 + sc) = vreg[hf];
    }
    __syncthreads();
    if (kt + 1 < ntiles) {
      const int k0n = (kt0 + kt + 1) * 64;
#pragma unroll
      for (int hf = 0; hf < 2; ++hf) {
        kreg[hf] = *(const s16x8*)(Kh + (size_t)(k0n + sr + hf * 32) * HD + sc);
        vreg[hf] = *(const s16x8*)(Vh + (size_t)(sr + hf * 32) * TSEQ + k0n + sc);
      }
    }

    f32x4 accS[2][4];
#pragma unroll
    for (int s = 0; s < 2; ++s)
#pragma unroll
      for (int n = 0; n < 4; ++n) accS[s][n] = f32x4{0.f, 0.f, 0.f, 0.f};
#pragma unroll
    for (int ks = 0; ks < 2; ++ks) {
#pragma unroll
      for (int n = 0; n < 4; ++n) {
        s16x8 kf = *(const s16x8*)(Ksh + (n * 16 + l15) * 72 + ks * 32 + quad * 8);
#pragma unroll
        for (int s = 0; s < 2; ++s)
          accS[s][n] = __builtin_amdgcn_mfma_f32_16x16x32_bf16(kf, qf[s][ks], accS[s][n], 0, 0, 0);
      }
    }

    // raw v_exp_f32 (R10-verified: libm exp2f's fixup was the VALU bottleneck)
    f16x4 pB[2][4];
#pragma unroll
    for (int s = 0; s < 2; ++s)
#pragma unroll
      for (int n = 0; n < 4; ++n) {
        float e0 = __builtin_amdgcn_exp2f(accS[s][n][0]);
        float e1 = __builtin_amdgcn_exp2f(accS[s][n][1]);
        float e2 = __builtin_amdgcn_exp2f(accS[s][n][2]);
        float e3 = __builtin_amdgcn_exp2f(accS[s][n][3]);
        rsum[s] += (e0 + e1) + (e2 + e3);
        f16x2 lo = __builtin_bit_cast(f16x2, __builtin_amdgcn_cvt_pkrtz(e0, e1));
        f16x2 hi = __builtin_bit_cast(f16x2, __builtin_amdgcn_cvt_pkrtz(e2, e3));
        pB[s][n] = f16x4{lo[0], lo[1], hi[0], hi[1]};
      }

#pragma unroll
    for (int n = 0; n < 4; ++n) {
#pragma unroll
      for (int n2 = 0; n2 < 4; ++n2) {
        f16x4 vA = *(const f16x4*)(Vsh + (n2 * 16 + l15) * 72 + n * 16 + quad * 4);
#pragma unroll
        for (int s = 0; s < 2; ++s)
          accO[n2][s] = __builtin_amdgcn_mfma_f32_16x16x16f16(vA, pB[s][n], accO[n2][s], 0, 0, 0);
      }
    }
  }

#pragma unroll
  for (int s = 0; s < 2; ++s) {
    float t = rsum[s];
    t += __shfl_xor(t, 16, 64);
    t += __shfl_xor(t, 32, 64);
    rsum[s] = t;
  }

  if (lsplit) {
    const int slot = (part * BATCH + b) * NH + h;
    const size_t ob = (size_t)slot * TSEQ * HD;
#pragma unroll
    for (int s = 0; s < 2; ++s) {
      const int t = q0 + s * 16 + l15;
#pragma unroll
      for (int n2 = 0; n2 < 4; ++n2) {
        const int d0 = n2 * 16 + quad * 4;
        unsigned short o[4];
#pragma unroll
        for (int r = 0; r < 4; ++r) o[r] = f2bf(accO[n2][s][r]);
        *(s16x4*)(Opart + ob + (size_t)t * HD + d0) = *(const s16x4*)o;
      }
    }
    if (quad == 0) {
      const size_t rb = (size_t)slot * TSEQ;
#pragma unroll
      for (int s = 0; s < 2; ++s)
        rsumP[rb + q0 + s * 16 + l15] = rsum[s];
    }
  } else {
#pragma unroll
    for (int s = 0; s < 2; ++s) {
      const int t = q0 + s * 16 + l15;
      const float inv = 1.f / rsum[s];
#pragma unroll
      for (int n2 = 0; n2 < 4; ++n2) {
        const int d0 = n2 * 16 + quad * 4;
        unsigned short o[4];
#pragma unroll
        for (int r = 0; r < 4; ++r) o[r] = f2bf(accO[n2][s][r] * inv);
        *(s16x4*)(ctx + ((size_t)(b * TSEQ + t)) * HID + h * HD + d0) = *(const s16x4*)o;
      }
    }
  }
}

// ---------------- combine K-split parts: ctx = sum(O_p)/sum(r_p), bf16 ----------------
__global__ __launch_bounds__(256) void combine_k(
    const unsigned short* __restrict__ Opart, const float* __restrict__ rsumP,
    unsigned short* __restrict__ ctx, int nparts) {
  const int gtid = blockIdx.x * 256 + threadIdx.x;  // 524288 total
  const int d = (gtid & 7) * 8;
  const int rem = gtid >> 3;
  const int t = rem & 2047;
  const int bh = rem >> 11;          // b*NH + h  (0..31)
  float acc[8] = {0, 0, 0, 0, 0, 0, 0, 0};
  float rs = 0.f;
  for (int p = 0; p < nparts; ++p) {
    const int slot = p * 32 + bh;
    s16x8 a = *(const s16x8*)(Opart + ((size_t)slot * TSEQ + t) * HD + d);
#pragma unroll
    for (int j = 0; j < 8; ++j) acc[j] += bf2f(((const unsigned short*)&a)[j]);
    rs += rsumP[(size_t)slot * TSEQ + t];
  }
  const float inv = 1.f / rs;
  unsigned short o[8];
#pragma unroll
  for (int j = 0; j < 8; ++j) o[j] = f2bf(acc[j] * inv);
  const int b = bh >> 4, h = bh & 15;
  *(s16x8*)(ctx + ((size_t)(b * TSEQ + t)) * HID + h * HD + d) = *(const s16x8*)o;
}

// ---------------- In-place LayerNorm over rows of 1024 ----------------
__global__ __launch_bounds__(256) void ln_k(float* __restrict__ io,
                                            const float* __restrict__ gamma,
                                            const float* __restrict__ beta) {
  const int row = blockIdx.x, tid = threadIdx.x;
  float x[4]; float s = 0.f, s2 = 0.f;
#pragma unroll
  for (int i = 0; i < 4; ++i) {
    x[i] = io[(size_t)row * HID + tid + i * 256];
    s += x[i]; s2 += x[i] * x[i];
  }
#pragma unroll
  for (int off = 1; off < 64; off <<= 1) {
    s  += __shfl_xor(s, off, 64);
    s2 += __shfl_xor(s2, off, 64);
  }
  __shared__ float red[8];
  const int wave = tid >> 6;
  if ((tid & 63) == 0) { red[wave] = s; red[wave + 4] = s2; }
  __syncthreads();
  s  = red[0] + red[1] + red[2] + red[3];
  s2 = red[4] + red[5] + red[6] + red[7];
  const float mean = s * (1.f / HID);
  const float var  = s2 * (1.f / HID) - mean * mean;
  const float rstd = rsqrtf(var + 1e-6f);
#pragma unroll
  for (int i = 0; i < 4; ++i) {
    const int col = tid + i * 256;
    io[(size_t)row * HID + col] = (x[i] - mean) * rstd * gamma[col] + beta[col];
  }
}

extern "C" void kernel_launch(void* const* d_in, const int* in_sizes, int n_in,
                              void* d_out, int out_size, void* d_ws, size_t ws_size,
                              hipStream_t stream) {
  const float* h    = (const float*)d_in[0];
  const float* Wq   = (const float*)d_in[1];
  const float* bq   = (const float*)d_in[2];
  const float* Wk   = (const float*)d_in[3];
  const float* bk   = (const float*)d_in[4];
  const float* Wv   = (const float*)d_in[5];
  const float* bv   = (const float*)d_in[6];
  const float* Wo   = (const float*)d_in[7];
  const float* bo   = (const float*)d_in[8];
  const float* gamma = (const float*)d_in[9];
  const float* beta  = (const float*)d_in[10];
  float* out = (float*)d_out;

  unsigned short* hb   = (unsigned short*)d_ws;   // bf16 h; dead after gemm_qkv -> reused as ctx
  unsigned short* wqb  = hb  + 4194304;           // 4 weights contiguous
  unsigned short* wkb  = wqb + 1048576;
  unsigned short* wvb  = wkb + 1048576;
  unsigned short* wob  = wvb + 1048576;
  unsigned short* qb   = wob + 1048576;           // bf16 [B,NH,T,D]
  unsigned short* kb   = qb  + 4194304;
  unsigned short* vtf  = kb  + 4194304;           // f16 [B,NH,D,T], written by gemm_qkv directly
  unsigned short* Opart = vtf + 4194304;          // bf16 partials (2 parts x 8 MiB)
  unsigned short* ctxb = hb;                      // ctx aliases dead hb

  const size_t base = (size_t)(vtf + 4194304 - hb) * 2;  // bytes before Opart (40 MiB)
  int lsplit = 0;
  if (ws_size >= base + 2u * 8388608 + 2u * 262144) lsplit = 1;  // ~57 MiB
  const int nparts = 1 << lsplit;
  float* rsumP = (float*)(Opart + (size_t)nparts * 4194304);

  cast_all_k<<<8192, 256, 0, stream>>>(h, Wq, Wk, Wv, Wo, hb, wqb);
  gemm_qkv<<<dim3(16, 64), 256, 0, stream>>>(hb, wqb, wkb, wvb, bq, bk, bv, qb, kb, vtf);
  attn_k<<<dim3(TSEQ / 128, NH, BATCH << lsplit), 256, 0, stream>>>(
      qb, kb, vtf, ctxb, Opart, rsumP, lsplit, 32 >> lsplit);
  if (lsplit)
    combine_k<<<2048, 256, 0, stream>>>(Opart, rsumP, ctxb, nparts);
  gemm_out<<<dim3(16, 32), 256, 0, stream>>>(ctxb, wob, bo, h, out);
  ln_k<<<4096, 256, 0, stream>>>(out, gamma, beta);
}